// Round 1
// baseline (3174.834 us; speedup 1.0000x reference)
//
#include <hip/hip_runtime.h>
#include <math.h>

// Shapes
constexpr int BATCH = 16;
constexpr int CH    = 512;
constexpr int NPIX  = 625;   // 25*25 == 5*125
constexpr int HEADS = 8;
constexpr int HDIM  = 64;
constexpr int HIDD  = 2048;

constexpr float EPS_LN = 1e-5f;
constexpr float EPS_BN = 1e-5f;
constexpr float SCALE  = 0.125f;   // hd^-0.5, used by BOTH attentions

// ---------------------------------------------------------------------------
// Channel LayerNorm (torch-style: (x-mean)/(std+eps)*g + b, std = sqrt(biased var))
// One thread per spatial position, loop over C (coalesced across positions).
// ---------------------------------------------------------------------------
__global__ void ln_kernel(const float* __restrict__ x, const float* __restrict__ g,
                          const float* __restrict__ bt, float* __restrict__ y) {
  int i = blockIdx.x * blockDim.x + threadIdx.x;
  int b = blockIdx.y;
  if (i >= NPIX) return;
  const float* xb = x + ((size_t)b * CH) * NPIX + i;
  float s = 0.f, ss = 0.f;
  for (int c = 0; c < CH; ++c) {
    float v = xb[(size_t)c * NPIX];
    s += v; ss += v * v;
  }
  float mean = s * (1.0f / CH);
  float var  = ss * (1.0f / CH) - mean * mean;
  float inv  = 1.0f / (sqrtf(fmaxf(var, 0.0f)) + EPS_LN);
  float* yb = y + ((size_t)b * CH) * NPIX + i;
  for (int c = 0; c < CH; ++c) {
    float v = xb[(size_t)c * NPIX];
    yb[(size_t)c * NPIX] = (v - mean) * inv * g[c] + bt[c];
  }
}

// ---------------------------------------------------------------------------
// Three depthwise 3x3 convs (pad 1) in one pass over the input.
// Works for 25x25 (q/k/v) and 5x125 (spe) geometries.
// ---------------------------------------------------------------------------
__global__ void dwconv3_kernel(const float* __restrict__ src,
    const float* __restrict__ w0, const float* __restrict__ b0,
    const float* __restrict__ w1, const float* __restrict__ b1,
    const float* __restrict__ w2, const float* __restrict__ b2,
    float* __restrict__ d0, float* __restrict__ d1, float* __restrict__ d2,
    int Hc, int Wc) {
  size_t idx = (size_t)blockIdx.x * blockDim.x + threadIdx.x;
  size_t total = (size_t)BATCH * CH * Hc * Wc;
  if (idx >= total) return;
  int wp = (int)(idx % Wc);
  int hp = (int)((idx / Wc) % Hc);
  int c  = (int)((idx / ((size_t)Wc * Hc)) % CH);
  const float* f0 = w0 + c * 9;
  const float* f1 = w1 + c * 9;
  const float* f2 = w2 + c * 9;
  float a0 = 0.f, a1 = 0.f, a2 = 0.f;
  #pragma unroll
  for (int kh = -1; kh <= 1; ++kh) {
    int h2 = hp + kh; if (h2 < 0 || h2 >= Hc) continue;
    #pragma unroll
    for (int kw = -1; kw <= 1; ++kw) {
      int w2p = wp + kw; if (w2p < 0 || w2p >= Wc) continue;
      float v = src[idx + (size_t)kh * Wc + kw];
      int wi = (kh + 1) * 3 + (kw + 1);
      a0 += v * f0[wi]; a1 += v * f1[wi]; a2 += v * f2[wi];
    }
  }
  d0[idx] = a0 + b0[c];
  d1[idx] = a1 + b1[c];
  d2[idx] = a2 + b2[c];
}

// ---------------------------------------------------------------------------
// Per-head attention. q/k/v layout: [B][C][N] with C = head*64 + d.
// Block = 256 threads handles one (b, head, 16-row tile). Full softmax row
// (625) kept in LDS; K/V staged in 64-col tiles. Output written directly in
// the rearranged layout att_out[b][head*64+d][i] (i = seq pos).
// ---------------------------------------------------------------------------
__global__ __launch_bounds__(256) void head_attn_kernel(
    const float* __restrict__ q, const float* __restrict__ k,
    const float* __restrict__ v, float* __restrict__ o) {
  __shared__ float S[16][640];
  __shared__ float Qs[16][64];
  __shared__ float KVs[64][65];
  int t  = threadIdx.x;
  int i0 = blockIdx.x * 16;
  int h  = blockIdx.y;
  int b  = blockIdx.z;
  size_t bc0 = ((size_t)b * CH + h * HDIM) * NPIX;

  // stage Q rows (zero-fill invalid rows)
  for (int e = t; e < 16 * 64; e += 256) {
    int r = e >> 6, d = e & 63;
    Qs[r][d] = (i0 + r < NPIX) ? q[bc0 + (size_t)d * NPIX + i0 + r] : 0.f;
  }
  __syncthreads();

  int jq = t & 63;      // column (phase1) / d (phase3)
  int rg = t >> 6;      // wave id

  // phase 1: scores
  for (int jt = 0; jt < 10; ++jt) {
    int j0 = jt * 64;
    for (int e = t; e < 64 * 64; e += 256) {
      int d = e >> 6, j = e & 63;
      KVs[d][j] = (j0 + j < NPIX) ? k[bc0 + (size_t)d * NPIX + j0 + j] : 0.f;
    }
    __syncthreads();
    #pragma unroll
    for (int kk = 0; kk < 4; ++kk) {
      int r = rg + kk * 4;
      float dot = 0.f;
      #pragma unroll
      for (int d = 0; d < 64; ++d) dot += Qs[r][d] * KVs[d][jq];
      S[r][j0 + jq] = dot * SCALE;
    }
    __syncthreads();
  }

  // phase 2: softmax (wave rg owns rows rg, rg+4, rg+8, rg+12)
  int lane = t & 63;
  #pragma unroll
  for (int kk = 0; kk < 4; ++kk) {
    int r = rg + kk * 4;
    float m = -1e30f;
    for (int j = lane; j < NPIX; j += 64) m = fmaxf(m, S[r][j]);
    #pragma unroll
    for (int off = 32; off > 0; off >>= 1) m = fmaxf(m, __shfl_xor(m, off));
    float sum = 0.f;
    for (int j = lane; j < NPIX; j += 64) {
      float e = __expf(S[r][j] - m);
      S[r][j] = e;
      sum += e;
    }
    #pragma unroll
    for (int off = 32; off > 0; off >>= 1) sum += __shfl_xor(sum, off);
    float inv = 1.0f / sum;
    for (int j = lane; j < NPIX; j += 64) S[r][j] *= inv;
  }
  __syncthreads();

  // phase 3: O = P @ V ; thread owns (d = jq, rows rg+4k)
  float acc[4] = {0.f, 0.f, 0.f, 0.f};
  for (int jt = 0; jt < 10; ++jt) {
    int j0 = jt * 64;
    for (int e = t; e < 64 * 64; e += 256) {
      int d = e >> 6, j = e & 63;
      KVs[d][j] = (j0 + j < NPIX) ? v[bc0 + (size_t)d * NPIX + j0 + j] : 0.f;
    }
    __syncthreads();
    #pragma unroll
    for (int kk = 0; kk < 4; ++kk) {
      int r = rg + kk * 4;
      float a = acc[kk];
      #pragma unroll
      for (int j = 0; j < 64; ++j) a += S[r][j0 + j] * KVs[jq][j];
      acc[kk] = a;
    }
    __syncthreads();
  }
  #pragma unroll
  for (int kk = 0; kk < 4; ++kk) {
    int r = rg + kk * 4;
    if (i0 + r < NPIX) o[bc0 + (size_t)jq * NPIX + i0 + r] = acc[kk];
  }
}

// ---------------------------------------------------------------------------
// Channel attention scores: A[b] = softmax_d( spe_q[b] (512x625) @ spe_k[b]^T * scale )
// Block handles (b, 16-row tile of cq). NT contraction over n=625.
// ---------------------------------------------------------------------------
__global__ __launch_bounds__(256) void chan_attn_kernel(
    const float* __restrict__ sq, const float* __restrict__ sk,
    float* __restrict__ A) {
  __shared__ float S[16][512];
  __shared__ float Aq[16][64];
  __shared__ float Ak[64][65];
  int t  = threadIdx.x;
  int m0 = blockIdx.x * 16;
  int b  = blockIdx.y;
  const float* sqb = sq + (size_t)b * CH * NPIX;
  const float* skb = sk + (size_t)b * CH * NPIX;
  int jq = t & 63, rg = t >> 6;

  for (int jt = 0; jt < 8; ++jt) {
    int j0 = jt * 64;
    float acc[4] = {0.f, 0.f, 0.f, 0.f};
    for (int nt = 0; nt < 10; ++nt) {
      int n0 = nt * 64;
      for (int e = t; e < 16 * 64; e += 256) {
        int r = e >> 6, n = e & 63;
        Aq[r][n] = (n0 + n < NPIX) ? sqb[(size_t)(m0 + r) * NPIX + n0 + n] : 0.f;
      }
      for (int e = t; e < 64 * 64; e += 256) {
        int jj = e >> 6, n = e & 63;
        Ak[jj][n] = (n0 + n < NPIX) ? skb[(size_t)(j0 + jj) * NPIX + n0 + n] : 0.f;
      }
      __syncthreads();
      #pragma unroll
      for (int n = 0; n < 64; ++n) {
        float kv = Ak[jq][n];
        #pragma unroll
        for (int kk = 0; kk < 4; ++kk) acc[kk] += Aq[rg + kk * 4][n] * kv;
      }
      __syncthreads();
    }
    #pragma unroll
    for (int kk = 0; kk < 4; ++kk) S[rg + kk * 4][j0 + jq] = acc[kk] * SCALE;
  }
  __syncthreads();

  // softmax over 512 cols, write out
  int lane = t & 63;
  float* Ab = A + ((size_t)b * CH + m0) * CH;
  #pragma unroll
  for (int kk = 0; kk < 4; ++kk) {
    int r = rg + kk * 4;
    float m = -1e30f;
    for (int j = lane; j < CH; j += 64) m = fmaxf(m, S[r][j]);
    #pragma unroll
    for (int off = 32; off > 0; off >>= 1) m = fmaxf(m, __shfl_xor(m, off));
    float sum = 0.f;
    for (int j = lane; j < CH; j += 64) {
      float e = __expf(S[r][j] - m);
      S[r][j] = e;
      sum += e;
    }
    #pragma unroll
    for (int off = 32; off > 0; off >>= 1) sum += __shfl_xor(sum, off);
    float inv = 1.0f / sum;
    for (int j = lane; j < CH; j += 64) Ab[(size_t)r * CH + j] = S[r][j] * inv;
  }
}

// ---------------------------------------------------------------------------
// Tiled NN GEMM: C[b] = A[b] (MxK, row-major) @ B[b] (KxN, row-major)
// 64x64 tile, BK=16, 256 threads, 4x4 per thread. Fused epilogues:
//  EPI 0: none
//  EPI 1: v*scale[m] + shift[m] + res   (BN + residual)
//  EPI 2: gelu_exact(v + bias[m])
//  EPI 3: v + bias[m] + res             (res may alias C: in-place safe)
// ---------------------------------------------------------------------------
template <int EPI>
__global__ __launch_bounds__(256) void gemm_nn(
    const float* __restrict__ A, long long aStride,
    const float* __restrict__ Bm, long long bStride,
    float* __restrict__ Cm, long long cStride,
    int M, int K, int Nc,
    const float* __restrict__ p0, const float* __restrict__ p1,
    const float* __restrict__ res, long long resStride) {
  __shared__ float As[16][68];
  __shared__ float Bs[16][68];
  int t  = threadIdx.x;
  int tx = t & 15, ty = t >> 4;
  int n0 = blockIdx.x * 64, m0 = blockIdx.y * 64, b = blockIdx.z;
  const float* Ab = A  + (size_t)b * aStride;
  const float* Bb = Bm + (size_t)b * bStride;
  float acc[4][4] = {};
  for (int k0 = 0; k0 < K; k0 += 16) {
    #pragma unroll
    for (int e = t; e < 64 * 16; e += 256) {
      int m = e >> 4, kk = e & 15;
      As[kk][m] = Ab[(size_t)(m0 + m) * K + k0 + kk];
    }
    #pragma unroll
    for (int e = t; e < 16 * 64; e += 256) {
      int kk = e >> 6, n = e & 63;
      Bs[kk][n] = (n0 + n < Nc) ? Bb[(size_t)(k0 + kk) * Nc + n0 + n] : 0.f;
    }
    __syncthreads();
    #pragma unroll
    for (int kk = 0; kk < 16; ++kk) {
      float4 av = *(const float4*)&As[kk][ty * 4];
      float4 bv = *(const float4*)&Bs[kk][tx * 4];
      float aa[4] = {av.x, av.y, av.z, av.w};
      float bb[4] = {bv.x, bv.y, bv.z, bv.w};
      #pragma unroll
      for (int i2 = 0; i2 < 4; ++i2)
        #pragma unroll
        for (int j2 = 0; j2 < 4; ++j2)
          acc[i2][j2] += aa[i2] * bb[j2];
    }
    __syncthreads();
  }
  #pragma unroll
  for (int i2 = 0; i2 < 4; ++i2) {
    int m = m0 + ty * 4 + i2;
    float sc = 0.f, sh = 0.f, bi = 0.f;
    if (EPI == 1) { sc = p0[m]; sh = p1[m]; }
    if (EPI == 2 || EPI == 3) { bi = p0[m]; }
    #pragma unroll
    for (int j2 = 0; j2 < 4; ++j2) {
      int n = n0 + tx * 4 + j2;
      if (n >= Nc) continue;
      float vv = acc[i2][j2];
      if (EPI == 1) {
        vv = vv * sc + sh + res[(size_t)b * resStride + (size_t)m * Nc + n];
      } else if (EPI == 2) {
        vv += bi;
        vv = 0.5f * vv * (1.0f + erff(vv * 0.70710678118654752f));
      } else if (EPI == 3) {
        vv = vv + bi + res[(size_t)b * resStride + (size_t)m * Nc + n];
      }
      Cm[(size_t)b * cStride + (size_t)m * Nc + n] = vv;
    }
  }
}

// Fold BN (eval) into per-channel scale/shift.
__global__ void bn_prep(const float* __restrict__ g, const float* __restrict__ bt,
                        const float* __restrict__ mean, const float* __restrict__ var,
                        float* __restrict__ scale, float* __restrict__ shift) {
  int c = blockIdx.x * blockDim.x + threadIdx.x;
  if (c >= CH) return;
  float s = g[c] * rsqrtf(var[c] + EPS_BN);
  scale[c] = s;
  shift[c] = bt[c] - mean[c] * s;
}

// ---------------------------------------------------------------------------
extern "C" void kernel_launch(void* const* d_in, const int* in_sizes, int n_in,
                              void* d_out, int out_size, void* d_ws, size_t ws_size,
                              hipStream_t stream) {
  const float* x      = (const float*)d_in[0];
  const float* ln1_g  = (const float*)d_in[1];
  const float* ln1_b  = (const float*)d_in[2];
  const float* wq     = (const float*)d_in[3];
  const float* bq     = (const float*)d_in[4];
  const float* wk     = (const float*)d_in[5];
  const float* bk     = (const float*)d_in[6];
  const float* wv     = (const float*)d_in[7];
  const float* bv     = (const float*)d_in[8];
  const float* swq    = (const float*)d_in[9];
  const float* sbq    = (const float*)d_in[10];
  const float* swk    = (const float*)d_in[11];
  const float* sbk    = (const float*)d_in[12];
  const float* swv    = (const float*)d_in[13];
  const float* sbv    = (const float*)d_in[14];
  const float* proj_w = (const float*)d_in[15];
  const float* bn_g   = (const float*)d_in[16];
  const float* bn_b   = (const float*)d_in[17];
  const float* bn_m   = (const float*)d_in[18];
  const float* bn_v   = (const float*)d_in[19];
  const float* ln2_g  = (const float*)d_in[20];
  const float* ln2_b  = (const float*)d_in[21];
  const float* w1     = (const float*)d_in[22];
  const float* b1     = (const float*)d_in[23];
  const float* w2     = (const float*)d_in[24];
  const float* b2     = (const float*)d_in[25];

  float* ws = (float*)d_ws;
  const size_t SZ = (size_t)BATCH * CH * NPIX;  // 5,120,000 floats
  float* xln  = ws;            // buf0: xln -> A (B*C*C fits) -> y1ln
  float* qb   = ws + SZ;       // buf1: q  -> spe_q -> h1[0:SZ)
  float* kb   = ws + 2 * SZ;   // buf2: k  -> spe_k -> h1[SZ:2SZ)
  float* vb   = ws + 3 * SZ;   // buf3: v  -> spe_v -> h1[2SZ:3SZ)
  float* ab   = ws + 4 * SZ;   // buf4: att_out -> x_out -> h1[3SZ:4SZ)
  float* bnsc = ws + 5 * SZ;
  float* bnsh = bnsc + CH;
  float* Amat = xln;           // [B][C][C]
  float* y1ln = xln;
  float* h1   = qb;            // spans buf1..buf4 = B*HID*NPIX floats exactly
  float* y1   = (float*)d_out; // y1 lives in d_out; FF2 adds residual in place

  const long long sBC = (long long)CH * NPIX;

  // LN1
  ln_kernel<<<dim3(3, BATCH), 256, 0, stream>>>(x, ln1_g, ln1_b, xln);
  // q,k,v depthwise convs on 25x25
  size_t tot = SZ;
  dwconv3_kernel<<<(int)((tot + 255) / 256), 256, 0, stream>>>(
      xln, wq, bq, wk, bk, wv, bv, qb, kb, vb, 25, 25);
  // per-head attention -> att_out (rearranged layout)
  head_attn_kernel<<<dim3(40, HEADS, BATCH), 256, 0, stream>>>(qb, kb, vb, ab);
  // spe depthwise convs on 5x125 geometry
  dwconv3_kernel<<<(int)((tot + 255) / 256), 256, 0, stream>>>(
      ab, swq, sbq, swk, sbk, swv, sbv, qb, kb, vb, 5, 125);
  // channel attention scores + softmax -> Amat
  chan_attn_kernel<<<dim3(32, BATCH), 256, 0, stream>>>(qb, kb, Amat);
  // x_out = A @ spe_v -> ab
  gemm_nn<0><<<dim3(10, 8, BATCH), 256, 0, stream>>>(
      Amat, (long long)CH * CH, vb, sBC, ab, sBC, CH, CH, NPIX,
      nullptr, nullptr, nullptr, 0);
  // BN fold
  bn_prep<<<2, 256, 0, stream>>>(bn_g, bn_b, bn_m, bn_v, bnsc, bnsh);
  // y1 = x + BN(proj_w @ x_out) -> d_out
  gemm_nn<1><<<dim3(10, 8, BATCH), 256, 0, stream>>>(
      proj_w, 0LL, ab, sBC, y1, sBC, CH, CH, NPIX,
      bnsc, bnsh, x, sBC);
  // LN2
  ln_kernel<<<dim3(3, BATCH), 256, 0, stream>>>(y1, ln2_g, ln2_b, y1ln);
  // h1 = gelu(W1 @ y1ln + b1)
  gemm_nn<2><<<dim3(10, 32, BATCH), 256, 0, stream>>>(
      w1, 0LL, y1ln, sBC, h1, (long long)HIDD * NPIX, HIDD, CH, NPIX,
      b1, nullptr, nullptr, 0);
  // out = y1 + W2 @ h1 + b2  (in-place residual on d_out)
  gemm_nn<3><<<dim3(10, 8, BATCH), 256, 0, stream>>>(
      w2, 0LL, h1, (long long)HIDD * NPIX, (float*)d_out, sBC, CH, HIDD, NPIX,
      b2, nullptr, y1, sBC);
}

// Round 2
// 2008.751 us; speedup vs baseline: 1.5805x; 1.5805x over previous
//
#include <hip/hip_runtime.h>
#include <math.h>

// Shapes
constexpr int BATCH = 16;
constexpr int CH    = 512;
constexpr int NPIX  = 625;   // 25*25 == 5*125
constexpr int HEADS = 8;
constexpr int HDIM  = 64;
constexpr int HIDD  = 2048;

constexpr float EPS_LN = 1e-5f;
constexpr float EPS_BN = 1e-5f;
constexpr float SCALE  = 0.125f;   // hd^-0.5, used by BOTH attentions

typedef __bf16 bf16x8 __attribute__((ext_vector_type(8)));
typedef float  f32x4  __attribute__((ext_vector_type(4)));

// ---------------------------------------------------------------------------
// Channel LayerNorm (torch-style: (x-mean)/(std+eps)*g + b)
// ---------------------------------------------------------------------------
__global__ void ln_kernel(const float* __restrict__ x, const float* __restrict__ g,
                          const float* __restrict__ bt, float* __restrict__ y) {
  int i = blockIdx.x * blockDim.x + threadIdx.x;
  int b = blockIdx.y;
  if (i >= NPIX) return;
  const float* xb = x + ((size_t)b * CH) * NPIX + i;
  float s = 0.f, ss = 0.f;
  for (int c = 0; c < CH; ++c) {
    float v = xb[(size_t)c * NPIX];
    s += v; ss += v * v;
  }
  float mean = s * (1.0f / CH);
  float var  = ss * (1.0f / CH) - mean * mean;
  float inv  = 1.0f / (sqrtf(fmaxf(var, 0.0f)) + EPS_LN);
  float* yb = y + ((size_t)b * CH) * NPIX + i;
  for (int c = 0; c < CH; ++c) {
    float v = xb[(size_t)c * NPIX];
    yb[(size_t)c * NPIX] = (v - mean) * inv * g[c] + bt[c];
  }
}

// ---------------------------------------------------------------------------
// Three depthwise 3x3 convs (pad 1) in one pass over the input.
// ---------------------------------------------------------------------------
__global__ void dwconv3_kernel(const float* __restrict__ src,
    const float* __restrict__ w0, const float* __restrict__ b0,
    const float* __restrict__ w1, const float* __restrict__ b1,
    const float* __restrict__ w2, const float* __restrict__ b2,
    float* __restrict__ d0, float* __restrict__ d1, float* __restrict__ d2,
    int Hc, int Wc) {
  size_t idx = (size_t)blockIdx.x * blockDim.x + threadIdx.x;
  size_t total = (size_t)BATCH * CH * Hc * Wc;
  if (idx >= total) return;
  int wp = (int)(idx % Wc);
  int hp = (int)((idx / Wc) % Hc);
  int c  = (int)((idx / ((size_t)Wc * Hc)) % CH);
  const float* f0 = w0 + c * 9;
  const float* f1 = w1 + c * 9;
  const float* f2 = w2 + c * 9;
  float a0 = 0.f, a1 = 0.f, a2 = 0.f;
  #pragma unroll
  for (int kh = -1; kh <= 1; ++kh) {
    int h2 = hp + kh; if (h2 < 0 || h2 >= Hc) continue;
    #pragma unroll
    for (int kw = -1; kw <= 1; ++kw) {
      int w2p = wp + kw; if (w2p < 0 || w2p >= Wc) continue;
      float v = src[idx + (size_t)kh * Wc + kw];
      int wi = (kh + 1) * 3 + (kw + 1);
      a0 += v * f0[wi]; a1 += v * f1[wi]; a2 += v * f2[wi];
    }
  }
  d0[idx] = a0 + b0[c];
  d1[idx] = a1 + b1[c];
  d2[idx] = a2 + b2[c];
}

// ---------------------------------------------------------------------------
// Transpose+cast q,k: [b][h*64+d][n] f32 -> [bh][n][64] bf16 (LDS tiled).
// ---------------------------------------------------------------------------
__global__ __launch_bounds__(256) void qk_to_bf16T(
    const float* __restrict__ q, const float* __restrict__ k,
    __bf16* __restrict__ qT, __bf16* __restrict__ kT) {
  __shared__ __bf16 tq[64][65];
  __shared__ __bf16 tk[64][65];
  int bh = blockIdx.y;
  int n0 = blockIdx.x * 64;
  int b = bh >> 3, h = bh & 7;
  const float* qb = q + (size_t)(b * CH + h * HDIM) * NPIX;
  const float* kb = k + (size_t)(b * CH + h * HDIM) * NPIX;
  #pragma unroll
  for (int it = 0; it < 16; ++it) {
    int idx = threadIdx.x + it * 256;
    int d = idx >> 6, n = idx & 63;
    int nn = n0 + n;
    float qv = (nn < NPIX) ? qb[(size_t)d * NPIX + nn] : 0.f;
    float kv = (nn < NPIX) ? kb[(size_t)d * NPIX + nn] : 0.f;
    tq[n][d] = (__bf16)qv;
    tk[n][d] = (__bf16)kv;
  }
  __syncthreads();
  size_t obase = (size_t)bh * NPIX;
  #pragma unroll
  for (int it = 0; it < 16; ++it) {
    int idx = threadIdx.x + it * 256;
    int n = idx >> 6, d = idx & 63;
    int nn = n0 + n;
    if (nn < NPIX) {
      qT[(obase + nn) * 64 + d] = tq[n][d];
      kT[(obase + nn) * 64 + d] = tk[n][d];
    }
  }
}

// v: [c][625] f32 -> [c][640] bf16 (row-padded for 16B-aligned frag loads)
__global__ void v_to_bf16(const float* __restrict__ v, __bf16* __restrict__ v16) {
  int row = blockIdx.x;
  const float* src = v + (size_t)row * NPIX;
  __bf16* dst = v16 + (size_t)row * 640;
  for (int n = threadIdx.x; n < NPIX; n += 256) dst[n] = (__bf16)src[n];
}

// ---------------------------------------------------------------------------
// MFMA head attention. qT/kT: [bh][n][64] bf16; vB: [b*512+c][640] bf16.
// Block = 4 waves, one (b, h, 64-row q tile); wave owns 16 q rows.
// Online softmax; P routed through XOR-swizzled per-wave LDS; output
// transposed via LDS for coalesced stores into [b][h*64+d][n] f32.
// ---------------------------------------------------------------------------
__global__ __launch_bounds__(256) void head_attn_mfma(
    const __bf16* __restrict__ qT, const __bf16* __restrict__ kT,
    const __bf16* __restrict__ vB, float* __restrict__ out) {
  __shared__ __align__(16) unsigned char sm_p[4][2048];
  __shared__ float lds_o[4][64][17];
  int t = threadIdx.x;
  int w = t >> 6, lane = t & 63, g = lane >> 4, li = lane & 15;
  int h = blockIdx.y, b = blockIdx.z;
  int bh = b * HEADS + h;
  int i0w = blockIdx.x * 64 + w * 16;
  const __bf16* Qb = qT + (size_t)bh * NPIX * 64;
  const __bf16* Kb = kT + (size_t)bh * NPIX * 64;
  const __bf16* Vb = vB + (size_t)(b * CH + h * HDIM) * 640;

  // Q A-frags: lane holds Q[i0w+li][8g+j (+32)]
  bf16x8 aq0, aq1;
  {
    int qr = i0w + li; if (qr > NPIX - 1) qr = NPIX - 1;
    const __bf16* qp = Qb + (size_t)qr * 64 + 8 * g;
    aq0 = *(const bf16x8*)(qp);
    aq1 = *(const bf16x8*)(qp + 32);
  }

  f32x4 o[4];
  #pragma unroll
  for (int dg = 0; dg < 4; ++dg) o[dg] = (f32x4){0.f, 0.f, 0.f, 0.f};
  float m[4] = {-1e30f, -1e30f, -1e30f, -1e30f};
  float l[4] = {0.f, 0.f, 0.f, 0.f};

  for (int jt = 0; jt < 10; ++jt) {
    int j0 = jt * 64;
    // ---- S = Q @ K^T (4 col-groups of 16) ----
    f32x4 s[4];
    #pragma unroll
    for (int cg = 0; cg < 4; ++cg) {
      int kc = j0 + cg * 16 + li;
      int kcc = kc > NPIX - 1 ? NPIX - 1 : kc;
      const __bf16* kp = Kb + (size_t)kcc * 64 + 8 * g;
      bf16x8 bk0 = *(const bf16x8*)(kp);
      bf16x8 bk1 = *(const bf16x8*)(kp + 32);
      f32x4 acc = (f32x4){0.f, 0.f, 0.f, 0.f};
      acc = __builtin_amdgcn_mfma_f32_16x16x32_bf16(aq0, bk0, acc, 0, 0, 0);
      acc = __builtin_amdgcn_mfma_f32_16x16x32_bf16(aq1, bk1, acc, 0, 0, 0);
      acc = acc * SCALE;
      if (kc > NPIX - 1) {  // mask padded key columns
        acc[0] = -1e30f; acc[1] = -1e30f; acc[2] = -1e30f; acc[3] = -1e30f;
      }
      s[cg] = acc;
    }
    // ---- online softmax (rows 4g+rr; cols spread over 16 lanes) ----
    #pragma unroll
    for (int rr = 0; rr < 4; ++rr) {
      float mv = fmaxf(fmaxf(s[0][rr], s[1][rr]), fmaxf(s[2][rr], s[3][rr]));
      mv = fmaxf(mv, __shfl_xor(mv, 1));
      mv = fmaxf(mv, __shfl_xor(mv, 2));
      mv = fmaxf(mv, __shfl_xor(mv, 4));
      mv = fmaxf(mv, __shfl_xor(mv, 8));
      float mn = fmaxf(m[rr], mv);
      float corr = __expf(m[rr] - mn);
      m[rr] = mn;
      float rs = 0.f;
      #pragma unroll
      for (int cg = 0; cg < 4; ++cg) {
        float p = __expf(s[cg][rr] - mn);
        s[cg][rr] = p;
        rs += p;
      }
      rs += __shfl_xor(rs, 1);
      rs += __shfl_xor(rs, 2);
      rs += __shfl_xor(rs, 4);
      rs += __shfl_xor(rs, 8);
      l[rr] = l[rr] * corr + rs;
      #pragma unroll
      for (int dg = 0; dg < 4; ++dg) o[dg][rr] *= corr;
    }
    // ---- P -> swizzled per-wave LDS (bf16) ----
    #pragma unroll
    for (int cg = 0; cg < 4; ++cg) {
      #pragma unroll
      for (int rr = 0; rr < 4; ++rr) {
        int row = 4 * g + rr, col = cg * 16 + li;
        int off = (row * 128 + col * 2) ^ ((row & 7) << 4);
        *(__bf16*)(&sm_p[w][off]) = (__bf16)s[cg][rr];
      }
    }
    // ---- read P as A-frags (b128, swizzle-consistent) ----
    int off0 = li * 128 + ((16 * g) ^ ((li & 7) << 4));
    int off1 = li * 128 + ((16 * g + 64) ^ ((li & 7) << 4));
    bf16x8 pa0 = *(const bf16x8*)(&sm_p[w][off0]);
    bf16x8 pa1 = *(const bf16x8*)(&sm_p[w][off1]);
    // ---- O += P @ V ----
    const __bf16* vp = Vb + (size_t)li * 640 + j0 + 8 * g;
    #pragma unroll
    for (int dg = 0; dg < 4; ++dg) {
      const __bf16* vpp = vp + (size_t)dg * 16 * 640;
      bf16x8 bv0 = *(const bf16x8*)(vpp);
      bf16x8 bv1 = *(const bf16x8*)(vpp + 32);
      o[dg] = __builtin_amdgcn_mfma_f32_16x16x32_bf16(pa0, bv0, o[dg], 0, 0, 0);
      o[dg] = __builtin_amdgcn_mfma_f32_16x16x32_bf16(pa1, bv1, o[dg], 0, 0, 0);
    }
  }

  // ---- epilogue: normalize, transpose in LDS, coalesced store ----
  float invl[4];
  #pragma unroll
  for (int rr = 0; rr < 4; ++rr) invl[rr] = 1.0f / l[rr];
  #pragma unroll
  for (int dg = 0; dg < 4; ++dg) {
    #pragma unroll
    for (int rr = 0; rr < 4; ++rr)
      lds_o[w][dg * 16 + li][4 * g + rr] = o[dg][rr] * invl[rr];
  }
  size_t cbase = (size_t)(b * CH + h * HDIM);
  int n = i0w + li;
  #pragma unroll
  for (int dd = 0; dd < 16; ++dd) {
    int d = dd * 4 + g;
    if (n < NPIX) out[(cbase + d) * NPIX + n] = lds_o[w][d][li];
  }
}

// ---------------------------------------------------------------------------
// Channel attention scores: A[b] = softmax_d( spe_q (512x625) @ spe_k^T * scale )
// ---------------------------------------------------------------------------
__global__ __launch_bounds__(256) void chan_attn_kernel(
    const float* __restrict__ sq, const float* __restrict__ sk,
    float* __restrict__ A) {
  __shared__ float S[16][512];
  __shared__ float Aq[16][64];
  __shared__ float Ak[64][65];
  int t  = threadIdx.x;
  int m0 = blockIdx.x * 16;
  int b  = blockIdx.y;
  const float* sqb = sq + (size_t)b * CH * NPIX;
  const float* skb = sk + (size_t)b * CH * NPIX;
  int jq = t & 63, rg = t >> 6;

  for (int jt = 0; jt < 8; ++jt) {
    int j0 = jt * 64;
    float acc[4] = {0.f, 0.f, 0.f, 0.f};
    for (int nt = 0; nt < 10; ++nt) {
      int n0 = nt * 64;
      for (int e = t; e < 16 * 64; e += 256) {
        int r = e >> 6, nn = e & 63;
        Aq[r][nn] = (n0 + nn < NPIX) ? sqb[(size_t)(m0 + r) * NPIX + n0 + nn] : 0.f;
      }
      for (int e = t; e < 64 * 64; e += 256) {
        int jj = e >> 6, nn = e & 63;
        Ak[jj][nn] = (n0 + nn < NPIX) ? skb[(size_t)(j0 + jj) * NPIX + n0 + nn] : 0.f;
      }
      __syncthreads();
      #pragma unroll
      for (int nn = 0; nn < 64; ++nn) {
        float kv = Ak[jq][nn];
        #pragma unroll
        for (int kk = 0; kk < 4; ++kk) acc[kk] += Aq[rg + kk * 4][nn] * kv;
      }
      __syncthreads();
    }
    #pragma unroll
    for (int kk = 0; kk < 4; ++kk) S[rg + kk * 4][j0 + jq] = acc[kk] * SCALE;
  }
  __syncthreads();

  int lane = t & 63;
  float* Ab = A + ((size_t)b * CH + m0) * CH;
  #pragma unroll
  for (int kk = 0; kk < 4; ++kk) {
    int r = rg + kk * 4;
    float m = -1e30f;
    for (int j = lane; j < CH; j += 64) m = fmaxf(m, S[r][j]);
    #pragma unroll
    for (int off = 32; off > 0; off >>= 1) m = fmaxf(m, __shfl_xor(m, off));
    float sum = 0.f;
    for (int j = lane; j < CH; j += 64) {
      float e = __expf(S[r][j] - m);
      S[r][j] = e;
      sum += e;
    }
    #pragma unroll
    for (int off = 32; off > 0; off >>= 1) sum += __shfl_xor(sum, off);
    float inv = 1.0f / sum;
    for (int j = lane; j < CH; j += 64) Ab[(size_t)r * CH + j] = S[r][j] * inv;
  }
}

// ---------------------------------------------------------------------------
// Tiled NN GEMM with fused epilogues (see round 0).
// ---------------------------------------------------------------------------
template <int EPI>
__global__ __launch_bounds__(256) void gemm_nn(
    const float* __restrict__ A, long long aStride,
    const float* __restrict__ Bm, long long bStride,
    float* __restrict__ Cm, long long cStride,
    int M, int K, int Nc,
    const float* __restrict__ p0, const float* __restrict__ p1,
    const float* __restrict__ res, long long resStride) {
  __shared__ float As[16][68];
  __shared__ float Bs[16][68];
  int t  = threadIdx.x;
  int tx = t & 15, ty = t >> 4;
  int n0 = blockIdx.x * 64, m0 = blockIdx.y * 64, b = blockIdx.z;
  const float* Ab = A  + (size_t)b * aStride;
  const float* Bb = Bm + (size_t)b * bStride;
  float acc[4][4] = {};
  for (int k0 = 0; k0 < K; k0 += 16) {
    #pragma unroll
    for (int e = t; e < 64 * 16; e += 256) {
      int m = e >> 4, kk = e & 15;
      As[kk][m] = Ab[(size_t)(m0 + m) * K + k0 + kk];
    }
    #pragma unroll
    for (int e = t; e < 16 * 64; e += 256) {
      int kk = e >> 6, nn = e & 63;
      Bs[kk][nn] = (n0 + nn < Nc) ? Bb[(size_t)(k0 + kk) * Nc + n0 + nn] : 0.f;
    }
    __syncthreads();
    #pragma unroll
    for (int kk = 0; kk < 16; ++kk) {
      float4 av = *(const float4*)&As[kk][ty * 4];
      float4 bv = *(const float4*)&Bs[kk][tx * 4];
      float aa[4] = {av.x, av.y, av.z, av.w};
      float bb[4] = {bv.x, bv.y, bv.z, bv.w};
      #pragma unroll
      for (int i2 = 0; i2 < 4; ++i2)
        #pragma unroll
        for (int j2 = 0; j2 < 4; ++j2)
          acc[i2][j2] += aa[i2] * bb[j2];
    }
    __syncthreads();
  }
  #pragma unroll
  for (int i2 = 0; i2 < 4; ++i2) {
    int m = m0 + ty * 4 + i2;
    float sc = 0.f, sh = 0.f, bi = 0.f;
    if (EPI == 1) { sc = p0[m]; sh = p1[m]; }
    if (EPI == 2 || EPI == 3) { bi = p0[m]; }
    #pragma unroll
    for (int j2 = 0; j2 < 4; ++j2) {
      int nn = n0 + tx * 4 + j2;
      if (nn >= Nc) continue;
      float vv = acc[i2][j2];
      if (EPI == 1) {
        vv = vv * sc + sh + res[(size_t)b * resStride + (size_t)m * Nc + nn];
      } else if (EPI == 2) {
        vv += bi;
        vv = 0.5f * vv * (1.0f + erff(vv * 0.70710678118654752f));
      } else if (EPI == 3) {
        vv = vv + bi + res[(size_t)b * resStride + (size_t)m * Nc + nn];
      }
      Cm[(size_t)b * cStride + (size_t)m * Nc + nn] = vv;
    }
  }
}

// Fold BN (eval) into per-channel scale/shift.
__global__ void bn_prep(const float* __restrict__ g, const float* __restrict__ bt,
                        const float* __restrict__ mean, const float* __restrict__ var,
                        float* __restrict__ scale, float* __restrict__ shift) {
  int c = blockIdx.x * blockDim.x + threadIdx.x;
  if (c >= CH) return;
  float s = g[c] * rsqrtf(var[c] + EPS_BN);
  scale[c] = s;
  shift[c] = bt[c] - mean[c] * s;
}

// ---------------------------------------------------------------------------
extern "C" void kernel_launch(void* const* d_in, const int* in_sizes, int n_in,
                              void* d_out, int out_size, void* d_ws, size_t ws_size,
                              hipStream_t stream) {
  const float* x      = (const float*)d_in[0];
  const float* ln1_g  = (const float*)d_in[1];
  const float* ln1_b  = (const float*)d_in[2];
  const float* wq     = (const float*)d_in[3];
  const float* bq     = (const float*)d_in[4];
  const float* wk     = (const float*)d_in[5];
  const float* bk     = (const float*)d_in[6];
  const float* wv     = (const float*)d_in[7];
  const float* bv     = (const float*)d_in[8];
  const float* swq    = (const float*)d_in[9];
  const float* sbq    = (const float*)d_in[10];
  const float* swk    = (const float*)d_in[11];
  const float* sbk    = (const float*)d_in[12];
  const float* swv    = (const float*)d_in[13];
  const float* sbv    = (const float*)d_in[14];
  const float* proj_w = (const float*)d_in[15];
  const float* bn_g   = (const float*)d_in[16];
  const float* bn_b   = (const float*)d_in[17];
  const float* bn_m   = (const float*)d_in[18];
  const float* bn_v   = (const float*)d_in[19];
  const float* ln2_g  = (const float*)d_in[20];
  const float* ln2_b  = (const float*)d_in[21];
  const float* w1     = (const float*)d_in[22];
  const float* b1     = (const float*)d_in[23];
  const float* w2     = (const float*)d_in[24];
  const float* b2     = (const float*)d_in[25];

  float* ws = (float*)d_ws;
  const size_t SZ = (size_t)BATCH * CH * NPIX;  // 5,120,000 floats
  float* xln  = ws;            // buf0: xln -> qT/kT (bf16) -> Amat -> y1ln
  float* qb   = ws + SZ;       // buf1
  float* kb   = ws + 2 * SZ;   // buf2
  float* vb   = ws + 3 * SZ;   // buf3
  float* ab   = ws + 4 * SZ;   // buf4: att_out -> x_out -> h1 tail
  float* bnsc = ws + 5 * SZ;
  float* bnsh = bnsc + CH;
  float* Amat = xln;           // [B][C][C]
  float* y1ln = xln;
  float* h1   = qb;            // spans buf1..buf4 = B*HID*NPIX floats exactly
  float* y1   = (float*)d_out; // y1 lives in d_out; FF2 adds residual in place

  __bf16* qT  = (__bf16*)xln;                        // buf0 first half
  __bf16* kTp = qT + (size_t)BATCH * HEADS * NPIX * 64;  // buf0 second half
  __bf16* v16 = (__bf16*)d_out;                      // d_out as scratch pre-y1

  const long long sBC = (long long)CH * NPIX;

  // LN1
  ln_kernel<<<dim3(3, BATCH), 256, 0, stream>>>(x, ln1_g, ln1_b, xln);
  // q,k,v depthwise convs on 25x25
  size_t tot = SZ;
  dwconv3_kernel<<<(int)((tot + 255) / 256), 256, 0, stream>>>(
      xln, wq, bq, wk, bk, wv, bv, qb, kb, vb, 25, 25);
  // bf16 layout conversion for MFMA attention
  qk_to_bf16T<<<dim3(10, BATCH * HEADS), 256, 0, stream>>>(qb, kb, qT, kTp);
  v_to_bf16<<<dim3(BATCH * CH), 256, 0, stream>>>(vb, v16);
  // MFMA per-head attention -> att_out (rearranged [b][c][n] layout)
  head_attn_mfma<<<dim3(10, HEADS, BATCH), 256, 0, stream>>>(qT, kTp, v16, ab);
  // spe depthwise convs on 5x125 geometry
  dwconv3_kernel<<<(int)((tot + 255) / 256), 256, 0, stream>>>(
      ab, swq, sbq, swk, sbk, swv, sbv, qb, kb, vb, 5, 125);
  // channel attention scores + softmax -> Amat
  chan_attn_kernel<<<dim3(32, BATCH), 256, 0, stream>>>(qb, kb, Amat);
  // x_out = A @ spe_v -> ab
  gemm_nn<0><<<dim3(10, 8, BATCH), 256, 0, stream>>>(
      Amat, (long long)CH * CH, vb, sBC, ab, sBC, CH, CH, NPIX,
      nullptr, nullptr, nullptr, 0);
  // BN fold
  bn_prep<<<2, 256, 0, stream>>>(bn_g, bn_b, bn_m, bn_v, bnsc, bnsh);
  // y1 = x + BN(proj_w @ x_out) -> d_out
  gemm_nn<1><<<dim3(10, 8, BATCH), 256, 0, stream>>>(
      proj_w, 0LL, ab, sBC, y1, sBC, CH, CH, NPIX,
      bnsc, bnsh, x, sBC);
  // LN2
  ln_kernel<<<dim3(3, BATCH), 256, 0, stream>>>(y1, ln2_g, ln2_b, y1ln);
  // h1 = gelu(W1 @ y1ln + b1)
  gemm_nn<2><<<dim3(10, 32, BATCH), 256, 0, stream>>>(
      w1, 0LL, y1ln, sBC, h1, (long long)HIDD * NPIX, HIDD, CH, NPIX,
      b1, nullptr, nullptr, 0);
  // out = y1 + W2 @ h1 + b2  (in-place residual on d_out)
  gemm_nn<3><<<dim3(10, 8, BATCH), 256, 0, stream>>>(
      w2, 0LL, h1, (long long)HIDD * NPIX, (float*)d_out, sBC, CH, HIDD, NPIX,
      b2, nullptr, y1, sBC);
}

// Round 3
// 646.813 us; speedup vs baseline: 4.9084x; 3.1056x over previous
//
#include <hip/hip_runtime.h>
#include <math.h>

// Shapes
constexpr int BATCH = 16;
constexpr int CH    = 512;
constexpr int NPIX  = 625;   // 25*25 == 5*125
constexpr int HEADS = 8;
constexpr int HDIM  = 64;
constexpr int HIDD  = 2048;

constexpr float EPS_LN = 1e-5f;
constexpr float EPS_BN = 1e-5f;
constexpr float SCALE  = 0.125f;   // hd^-0.5, both attentions

typedef __bf16 bf16x8 __attribute__((ext_vector_type(8)));
typedef float  f32x4  __attribute__((ext_vector_type(4)));

// ---------------------------------------------------------------------------
// Channel LayerNorm (torch-style), input/output [b][c][n] f32. (unchanged)
// ---------------------------------------------------------------------------
__global__ void ln_kernel(const float* __restrict__ x, const float* __restrict__ g,
                          const float* __restrict__ bt, float* __restrict__ y) {
  int i = blockIdx.x * blockDim.x + threadIdx.x;
  int b = blockIdx.y;
  if (i >= NPIX) return;
  const float* xb = x + ((size_t)b * CH) * NPIX + i;
  float s = 0.f, ss = 0.f;
  for (int c = 0; c < CH; ++c) {
    float v = xb[(size_t)c * NPIX];
    s += v; ss += v * v;
  }
  float mean = s * (1.0f / CH);
  float var  = ss * (1.0f / CH) - mean * mean;
  float inv  = 1.0f / (sqrtf(fmaxf(var, 0.0f)) + EPS_LN);
  float* yb = y + ((size_t)b * CH) * NPIX + i;
  for (int c = 0; c < CH; ++c) {
    float v = xb[(size_t)c * NPIX];
    yb[(size_t)c * NPIX] = (v - mean) * inv * g[c] + bt[c];
  }
}

// ---------------------------------------------------------------------------
// First depthwise conv (25x25): three convs in one pass, f32 out. (unchanged)
// ---------------------------------------------------------------------------
__global__ void dwconv3_kernel(const float* __restrict__ src,
    const float* __restrict__ w0, const float* __restrict__ b0,
    const float* __restrict__ w1, const float* __restrict__ b1,
    const float* __restrict__ w2, const float* __restrict__ b2,
    float* __restrict__ d0, float* __restrict__ d1, float* __restrict__ d2,
    int Hc, int Wc) {
  size_t idx = (size_t)blockIdx.x * blockDim.x + threadIdx.x;
  size_t total = (size_t)BATCH * CH * Hc * Wc;
  if (idx >= total) return;
  int wp = (int)(idx % Wc);
  int hp = (int)((idx / Wc) % Hc);
  int c  = (int)((idx / ((size_t)Wc * Hc)) % CH);
  const float* f0 = w0 + c * 9;
  const float* f1 = w1 + c * 9;
  const float* f2 = w2 + c * 9;
  float a0 = 0.f, a1 = 0.f, a2 = 0.f;
  #pragma unroll
  for (int kh = -1; kh <= 1; ++kh) {
    int h2 = hp + kh; if (h2 < 0 || h2 >= Hc) continue;
    #pragma unroll
    for (int kw = -1; kw <= 1; ++kw) {
      int w2p = wp + kw; if (w2p < 0 || w2p >= Wc) continue;
      float v = src[idx + (size_t)kh * Wc + kw];
      int wi = (kh + 1) * 3 + (kw + 1);
      a0 += v * f0[wi]; a1 += v * f1[wi]; a2 += v * f2[wi];
    }
  }
  d0[idx] = a0 + b0[c];
  d1[idx] = a1 + b1[c];
  d2[idx] = a2 + b2[c];
}

// ---------------------------------------------------------------------------
// spe depthwise conv (5x125) on att_out [c][625] f32:
// q,k -> bf16 [c][640] zero-padded; v -> f32 [c][625].
// ---------------------------------------------------------------------------
__global__ void dwconv_spe_kernel(const float* __restrict__ src,
    const float* __restrict__ w0, const float* __restrict__ b0,
    const float* __restrict__ w1, const float* __restrict__ b1,
    const float* __restrict__ w2, const float* __restrict__ b2,
    __bf16* __restrict__ q16, __bf16* __restrict__ k16, float* __restrict__ v) {
  size_t idx = (size_t)blockIdx.x * blockDim.x + threadIdx.x;
  if (idx >= (size_t)BATCH * CH * 640) return;
  int n = (int)(idx % 640);
  int c = (int)((idx / 640) % CH);
  int b = (int)(idx / ((size_t)640 * CH));
  if (n >= NPIX) { q16[idx] = (__bf16)0.f; k16[idx] = (__bf16)0.f; return; }
  int hp = n / 125, wp = n % 125;
  size_t base = ((size_t)b * CH + c) * NPIX;
  const float* f0 = w0 + c * 9;
  const float* f1 = w1 + c * 9;
  const float* f2 = w2 + c * 9;
  float a0 = 0.f, a1 = 0.f, a2 = 0.f;
  #pragma unroll
  for (int kh = -1; kh <= 1; ++kh) {
    int h2 = hp + kh; if (h2 < 0 || h2 >= 5) continue;
    #pragma unroll
    for (int kw = -1; kw <= 1; ++kw) {
      int w2p = wp + kw; if (w2p < 0 || w2p >= 125) continue;
      float vv = src[base + h2 * 125 + w2p];
      int wi = (kh + 1) * 3 + (kw + 1);
      a0 += vv * f0[wi]; a1 += vv * f1[wi]; a2 += vv * f2[wi];
    }
  }
  q16[idx] = (__bf16)(a0 + b0[c]);
  k16[idx] = (__bf16)(a1 + b1[c]);
  v[base + n] = a2 + b2[c];
}

// ---------------------------------------------------------------------------
// Transpose+cast q,k: [b][h*64+d][n] f32 -> [bh][n][64] bf16. (unchanged)
// ---------------------------------------------------------------------------
__global__ __launch_bounds__(256) void qk_to_bf16T(
    const float* __restrict__ q, const float* __restrict__ k,
    __bf16* __restrict__ qT, __bf16* __restrict__ kT) {
  __shared__ __bf16 tq[64][65];
  __shared__ __bf16 tk[64][65];
  int bh = blockIdx.y;
  int n0 = blockIdx.x * 64;
  int b = bh >> 3, h = bh & 7;
  const float* qb = q + (size_t)(b * CH + h * HDIM) * NPIX;
  const float* kb = k + (size_t)(b * CH + h * HDIM) * NPIX;
  #pragma unroll
  for (int it = 0; it < 16; ++it) {
    int idx = threadIdx.x + it * 256;
    int d = idx >> 6, n = idx & 63;
    int nn = n0 + n;
    float qv = (nn < NPIX) ? qb[(size_t)d * NPIX + nn] : 0.f;
    float kv = (nn < NPIX) ? kb[(size_t)d * NPIX + nn] : 0.f;
    tq[n][d] = (__bf16)qv;
    tk[n][d] = (__bf16)kv;
  }
  __syncthreads();
  size_t obase = (size_t)bh * NPIX;
  #pragma unroll
  for (int it = 0; it < 16; ++it) {
    int idx = threadIdx.x + it * 256;
    int n = idx >> 6, d = idx & 63;
    int nn = n0 + n;
    if (nn < NPIX) {
      qT[(obase + nn) * 64 + d] = tq[n][d];
      kT[(obase + nn) * 64 + d] = tk[n][d];
    }
  }
}

// v: [c][625] f32 -> [c][640] bf16 (n>=625 left as-is; masked by P=0). (unchanged)
__global__ void v_to_bf16(const float* __restrict__ v, __bf16* __restrict__ v16) {
  int row = blockIdx.x;
  const float* src = v + (size_t)row * NPIX;
  __bf16* dst = v16 + (size_t)row * 640;
  for (int n = threadIdx.x; n < NPIX; n += 256) dst[n] = (__bf16)src[n];
}

// ---------------------------------------------------------------------------
// MFMA head attention (unchanged, verified round 1).
// ---------------------------------------------------------------------------
__global__ __launch_bounds__(256) void head_attn_mfma(
    const __bf16* __restrict__ qT, const __bf16* __restrict__ kT,
    const __bf16* __restrict__ vB, float* __restrict__ out) {
  __shared__ __align__(16) unsigned char sm_p[4][2048];
  __shared__ float lds_o[4][64][17];
  int t = threadIdx.x;
  int w = t >> 6, lane = t & 63, g = lane >> 4, li = lane & 15;
  int h = blockIdx.y, b = blockIdx.z;
  int bh = b * HEADS + h;
  int i0w = blockIdx.x * 64 + w * 16;
  const __bf16* Qb = qT + (size_t)bh * NPIX * 64;
  const __bf16* Kb = kT + (size_t)bh * NPIX * 64;
  const __bf16* Vb = vB + (size_t)(b * CH + h * HDIM) * 640;

  bf16x8 aq0, aq1;
  {
    int qr = i0w + li; if (qr > NPIX - 1) qr = NPIX - 1;
    const __bf16* qp = Qb + (size_t)qr * 64 + 8 * g;
    aq0 = *(const bf16x8*)(qp);
    aq1 = *(const bf16x8*)(qp + 32);
  }

  f32x4 o[4];
  #pragma unroll
  for (int dg = 0; dg < 4; ++dg) o[dg] = (f32x4){0.f, 0.f, 0.f, 0.f};
  float m[4] = {-1e30f, -1e30f, -1e30f, -1e30f};
  float l[4] = {0.f, 0.f, 0.f, 0.f};

  for (int jt = 0; jt < 10; ++jt) {
    int j0 = jt * 64;
    f32x4 s[4];
    #pragma unroll
    for (int cg = 0; cg < 4; ++cg) {
      int kc = j0 + cg * 16 + li;
      int kcc = kc > NPIX - 1 ? NPIX - 1 : kc;
      const __bf16* kp = Kb + (size_t)kcc * 64 + 8 * g;
      bf16x8 bk0 = *(const bf16x8*)(kp);
      bf16x8 bk1 = *(const bf16x8*)(kp + 32);
      f32x4 acc = (f32x4){0.f, 0.f, 0.f, 0.f};
      acc = __builtin_amdgcn_mfma_f32_16x16x32_bf16(aq0, bk0, acc, 0, 0, 0);
      acc = __builtin_amdgcn_mfma_f32_16x16x32_bf16(aq1, bk1, acc, 0, 0, 0);
      acc = acc * SCALE;
      if (kc > NPIX - 1) {
        acc[0] = -1e30f; acc[1] = -1e30f; acc[2] = -1e30f; acc[3] = -1e30f;
      }
      s[cg] = acc;
    }
    #pragma unroll
    for (int rr = 0; rr < 4; ++rr) {
      float mv = fmaxf(fmaxf(s[0][rr], s[1][rr]), fmaxf(s[2][rr], s[3][rr]));
      mv = fmaxf(mv, __shfl_xor(mv, 1));
      mv = fmaxf(mv, __shfl_xor(mv, 2));
      mv = fmaxf(mv, __shfl_xor(mv, 4));
      mv = fmaxf(mv, __shfl_xor(mv, 8));
      float mn = fmaxf(m[rr], mv);
      float corr = __expf(m[rr] - mn);
      m[rr] = mn;
      float rs = 0.f;
      #pragma unroll
      for (int cg = 0; cg < 4; ++cg) {
        float p = __expf(s[cg][rr] - mn);
        s[cg][rr] = p;
        rs += p;
      }
      rs += __shfl_xor(rs, 1);
      rs += __shfl_xor(rs, 2);
      rs += __shfl_xor(rs, 4);
      rs += __shfl_xor(rs, 8);
      l[rr] = l[rr] * corr + rs;
      #pragma unroll
      for (int dg = 0; dg < 4; ++dg) o[dg][rr] *= corr;
    }
    #pragma unroll
    for (int cg = 0; cg < 4; ++cg) {
      #pragma unroll
      for (int rr = 0; rr < 4; ++rr) {
        int row = 4 * g + rr, col = cg * 16 + li;
        int off = (row * 128 + col * 2) ^ ((row & 7) << 4);
        *(__bf16*)(&sm_p[w][off]) = (__bf16)s[cg][rr];
      }
    }
    int off0 = li * 128 + ((16 * g) ^ ((li & 7) << 4));
    int off1 = li * 128 + ((16 * g + 64) ^ ((li & 7) << 4));
    bf16x8 pa0 = *(const bf16x8*)(&sm_p[w][off0]);
    bf16x8 pa1 = *(const bf16x8*)(&sm_p[w][off1]);
    const __bf16* vp = Vb + (size_t)li * 640 + j0 + 8 * g;
    #pragma unroll
    for (int dg = 0; dg < 4; ++dg) {
      const __bf16* vpp = vp + (size_t)dg * 16 * 640;
      bf16x8 bv0 = *(const bf16x8*)(vpp);
      bf16x8 bv1 = *(const bf16x8*)(vpp + 32);
      o[dg] = __builtin_amdgcn_mfma_f32_16x16x32_bf16(pa0, bv0, o[dg], 0, 0, 0);
      o[dg] = __builtin_amdgcn_mfma_f32_16x16x32_bf16(pa1, bv1, o[dg], 0, 0, 0);
    }
  }

  float invl[4];
  #pragma unroll
  for (int rr = 0; rr < 4; ++rr) invl[rr] = 1.0f / l[rr];
  #pragma unroll
  for (int dg = 0; dg < 4; ++dg) {
    #pragma unroll
    for (int rr = 0; rr < 4; ++rr)
      lds_o[w][dg * 16 + li][4 * g + rr] = o[dg][rr] * invl[rr];
  }
  size_t cbase = (size_t)(b * CH + h * HDIM);
  int n = i0w + li;
  #pragma unroll
  for (int dd = 0; dd < 16; ++dd) {
    int d = dd * 4 + g;
    if (n < NPIX) out[(cbase + d) * NPIX + n] = lds_o[w][d][li];
  }
}

// ---------------------------------------------------------------------------
// MFMA channel attention: Amat[b][cq][ck] = softmax_ck(q.k^T * scale), bf16 out.
// One wave per 16 rows; full 512-col row in 32 acc frags; K = n (640, padded 0).
// ---------------------------------------------------------------------------
__global__ __launch_bounds__(64) void chan_attn_mfma(
    const __bf16* __restrict__ sq, const __bf16* __restrict__ sk,
    __bf16* __restrict__ Am) {
  int lane = threadIdx.x & 63;
  int g = lane >> 4, li = lane & 15;
  int b = blockIdx.y;
  int cq0 = blockIdx.x * 16;
  const __bf16* qrow  = sq + ((size_t)b * CH + cq0 + li) * 640 + 8 * g;
  const __bf16* kbase = sk + ((size_t)b * CH + li) * 640 + 8 * g;
  f32x4 acc[32];
  #pragma unroll
  for (int i = 0; i < 32; ++i) acc[i] = (f32x4){0.f, 0.f, 0.f, 0.f};
  for (int ks = 0; ks < 20; ++ks) {
    bf16x8 af = *(const bf16x8*)(qrow + ks * 32);
    #pragma unroll
    for (int cf = 0; cf < 32; ++cf) {
      bf16x8 bfr = *(const bf16x8*)(kbase + (size_t)cf * 16 * 640 + ks * 32);
      acc[cf] = __builtin_amdgcn_mfma_f32_16x16x32_bf16(af, bfr, acc[cf], 0, 0, 0);
    }
  }
  #pragma unroll
  for (int i = 0; i < 32; ++i) acc[i] = acc[i] * SCALE;
  __bf16* Ab = Am + ((size_t)b * CH + cq0) * CH;
  #pragma unroll
  for (int r = 0; r < 4; ++r) {
    float mx = -1e30f;
    #pragma unroll
    for (int cf = 0; cf < 32; ++cf) mx = fmaxf(mx, acc[cf][r]);
    mx = fmaxf(mx, __shfl_xor(mx, 1));
    mx = fmaxf(mx, __shfl_xor(mx, 2));
    mx = fmaxf(mx, __shfl_xor(mx, 4));
    mx = fmaxf(mx, __shfl_xor(mx, 8));
    float sum = 0.f;
    #pragma unroll
    for (int cf = 0; cf < 32; ++cf) {
      float p = __expf(acc[cf][r] - mx);
      acc[cf][r] = p;
      sum += p;
    }
    sum += __shfl_xor(sum, 1);
    sum += __shfl_xor(sum, 2);
    sum += __shfl_xor(sum, 4);
    sum += __shfl_xor(sum, 8);
    float inv = 1.0f / sum;
    #pragma unroll
    for (int cf = 0; cf < 32; ++cf)
      Ab[(size_t)(4 * g + r) * CH + cf * 16 + li] = (__bf16)(acc[cf][r] * inv);
  }
}

// ---------------------------------------------------------------------------
// NT bf16 MFMA GEMM: C[m][n] = sum_k A[m][k] * B[n][k]  (both K-contiguous).
// BM=128, BN=64, BK=64; 4 waves (2x2), wave = 64x32; XOR-swizzled LDS;
// LDS-transpose epilogue -> row-major stores. EPI:
//   0: bf16 store   1: v*p0[n]+p1[n]+res f32   2: gelu(v+p0[n]) bf16
//   3: v+p0[n]+res f32
// ---------------------------------------------------------------------------
template <int EPI>
__global__ __launch_bounds__(256) void gemm_nt(
    const __bf16* __restrict__ A, long long aBatch,
    const __bf16* __restrict__ B, long long bBatch,
    void* __restrict__ Cout, long long cBatch,
    int M, int N, int K,
    const float* __restrict__ p0, const float* __restrict__ p1,
    const float* __restrict__ res, long long resBatch) {
  __shared__ __align__(16) union {
    struct { unsigned char As[128 * 128]; unsigned char Bs[64 * 128]; } s;
    float Ce[4][64][17];
  } u;
  int t = threadIdx.x;
  int w = t >> 6, lane = t & 63, g = lane >> 4, li = lane & 15;
  int wm = w & 1, wn = w >> 1;
  int n0 = blockIdx.x * 64, m0 = blockIdx.y * 128, b = blockIdx.z;
  const __bf16* Ab = A + (size_t)b * aBatch;
  const __bf16* Bb = B + (size_t)b * bBatch;
  f32x4 acc[4][2];
  #pragma unroll
  for (int i = 0; i < 4; ++i)
    #pragma unroll
    for (int j = 0; j < 2; ++j) acc[i][j] = (f32x4){0.f, 0.f, 0.f, 0.f};

  for (int k0 = 0; k0 < K; k0 += 64) {
    bf16x8 ra[4], rb[2];
    #pragma unroll
    for (int i = 0; i < 4; ++i) {
      int e = t + i * 256;
      int row = e >> 3, cc = e & 7;
      int ar = m0 + row; ar = ar < M ? ar : M - 1;
      ra[i] = *(const bf16x8*)(Ab + (size_t)ar * K + k0 + cc * 8);
    }
    #pragma unroll
    for (int i = 0; i < 2; ++i) {
      int e = t + i * 256;
      int row = e >> 3, cc = e & 7;
      rb[i] = *(const bf16x8*)(Bb + (size_t)(n0 + row) * K + k0 + cc * 8);
    }
    __syncthreads();
    #pragma unroll
    for (int i = 0; i < 4; ++i) {
      int e = t + i * 256; int row = e >> 3, cc = e & 7;
      int off = (row * 128 + cc * 16) ^ ((row & 7) << 4);
      *(bf16x8*)(&u.s.As[off]) = ra[i];
    }
    #pragma unroll
    for (int i = 0; i < 2; ++i) {
      int e = t + i * 256; int row = e >> 3, cc = e & 7;
      int off = (row * 128 + cc * 16) ^ ((row & 7) << 4);
      *(bf16x8*)(&u.s.Bs[off]) = rb[i];
    }
    __syncthreads();
    #pragma unroll
    for (int ks = 0; ks < 2; ++ks) {
      bf16x8 af[4], bfr[2];
      #pragma unroll
      for (int mf = 0; mf < 4; ++mf) {
        int row = wm * 64 + mf * 16 + li;
        int off = (row * 128 + ks * 64 + g * 16) ^ ((row & 7) << 4);
        af[mf] = *(const bf16x8*)(&u.s.As[off]);
      }
      #pragma unroll
      for (int nf = 0; nf < 2; ++nf) {
        int row = wn * 32 + nf * 16 + li;
        int off = (row * 128 + ks * 64 + g * 16) ^ ((row & 7) << 4);
        bfr[nf] = *(const bf16x8*)(&u.s.Bs[off]);
      }
      #pragma unroll
      for (int mf = 0; mf < 4; ++mf)
        #pragma unroll
        for (int nf = 0; nf < 2; ++nf)
          acc[mf][nf] = __builtin_amdgcn_mfma_f32_16x16x32_bf16(
              af[mf], bfr[nf], acc[mf][nf], 0, 0, 0);
    }
    __syncthreads();
  }

  // epilogue: per wave, stage 64x16 tiles, read rows, fused op, store row-major
  #pragma unroll
  for (int p = 0; p < 2; ++p) {
    __syncthreads();
    #pragma unroll
    for (int mf = 0; mf < 4; ++mf) {
      #pragma unroll
      for (int r = 0; r < 4; ++r)
        u.Ce[w][mf * 16 + 4 * g + r][li] = acc[mf][p][r];
    }
    __syncthreads();
    int m = m0 + wm * 64 + lane;
    int colb = n0 + wn * 32 + p * 16;
    if (m < M) {
      float vv[16];
      #pragma unroll
      for (int c = 0; c < 16; ++c) vv[c] = u.Ce[w][lane][c];
      if (EPI == 0) {
        __bf16* Cb = (__bf16*)Cout + (size_t)b * cBatch + (size_t)m * N + colb;
        bf16x8 o0, o1;
        #pragma unroll
        for (int j = 0; j < 8; ++j) { o0[j] = (__bf16)vv[j]; o1[j] = (__bf16)vv[8 + j]; }
        *(bf16x8*)(Cb) = o0;
        *(bf16x8*)(Cb + 8) = o1;
      } else if (EPI == 1) {
        float* Cf = (float*)Cout + (size_t)b * cBatch + (size_t)m * N + colb;
        const float* rp = res + (size_t)b * resBatch + (size_t)m * N + colb;
        #pragma unroll
        for (int c = 0; c < 16; ++c)
          vv[c] = vv[c] * p0[colb + c] + p1[colb + c] + rp[c];
        #pragma unroll
        for (int c4 = 0; c4 < 4; ++c4)
          *(f32x4*)(Cf + c4 * 4) = (f32x4){vv[c4*4], vv[c4*4+1], vv[c4*4+2], vv[c4*4+3]};
      } else if (EPI == 2) {
        __bf16* Cb = (__bf16*)Cout + (size_t)b * cBatch + (size_t)m * N + colb;
        #pragma unroll
        for (int c = 0; c < 16; ++c) {
          float xg = vv[c] + p0[colb + c];
          vv[c] = 0.5f * xg * (1.0f + erff(xg * 0.70710678118654752f));
        }
        bf16x8 o0, o1;
        #pragma unroll
        for (int j = 0; j < 8; ++j) { o0[j] = (__bf16)vv[j]; o1[j] = (__bf16)vv[8 + j]; }
        *(bf16x8*)(Cb) = o0;
        *(bf16x8*)(Cb + 8) = o1;
      } else {
        float* Cf = (float*)Cout + (size_t)b * cBatch + (size_t)m * N + colb;
        const float* rp = res + (size_t)b * resBatch + (size_t)m * N + colb;
        #pragma unroll
        for (int c = 0; c < 16; ++c)
          vv[c] = vv[c] + p0[colb + c] + rp[c];
        #pragma unroll
        for (int c4 = 0; c4 < 4; ++c4)
          *(f32x4*)(Cf + c4 * 4) = (f32x4){vv[c4*4], vv[c4*4+1], vv[c4*4+2], vv[c4*4+3]};
      }
    }
  }
}

// ---------------------------------------------------------------------------
// Batched tiled transpose: in [b][R][Cc] f32 -> out [b][Cc][R] (TO = f32/bf16)
// ---------------------------------------------------------------------------
template <typename TO>
__global__ __launch_bounds__(256) void transpose_bat(
    const float* __restrict__ in, TO* __restrict__ out, int R, int Cc) {
  __shared__ float tile[64][65];
  int b = blockIdx.z;
  int c0 = blockIdx.x * 64, r0 = blockIdx.y * 64;
  const float* ib = in + (size_t)b * R * Cc;
  TO* ob = out + (size_t)b * R * Cc;
  for (int e = threadIdx.x; e < 4096; e += 256) {
    int rr = e >> 6, cc = e & 63;
    int r = r0 + rr, c = c0 + cc;
    tile[rr][cc] = (r < R && c < Cc) ? ib[(size_t)r * Cc + c] : 0.f;
  }
  __syncthreads();
  for (int e = threadIdx.x; e < 4096; e += 256) {
    int cc = e >> 6, rr = e & 63;
    int r = r0 + rr, c = c0 + cc;
    if (r < R && c < Cc) ob[(size_t)c * R + r] = (TO)tile[rr][cc];
  }
}

// ---------------------------------------------------------------------------
// Row LayerNorm: y1_nc f32 [10000][512] -> bf16 [10000][512]. 1 wave / row.
// ---------------------------------------------------------------------------
__global__ __launch_bounds__(256) void ln2_row_kernel(
    const float* __restrict__ y, const float* __restrict__ g,
    const float* __restrict__ bt, __bf16* __restrict__ o) {
  int row = blockIdx.x * 4 + (threadIdx.x >> 6);
  int lane = threadIdx.x & 63;
  const float* yr = y + (size_t)row * CH + lane * 8;
  f32x4 v0 = *(const f32x4*)(yr);
  f32x4 v1 = *(const f32x4*)(yr + 4);
  float s = v0[0]+v0[1]+v0[2]+v0[3]+v1[0]+v1[1]+v1[2]+v1[3];
  float ss = v0[0]*v0[0]+v0[1]*v0[1]+v0[2]*v0[2]+v0[3]*v0[3]
           + v1[0]*v1[0]+v1[1]*v1[1]+v1[2]*v1[2]+v1[3]*v1[3];
  #pragma unroll
  for (int off = 32; off > 0; off >>= 1) {
    s  += __shfl_xor(s, off);
    ss += __shfl_xor(ss, off);
  }
  float mean = s * (1.0f / CH);
  float var  = ss * (1.0f / CH) - mean * mean;
  float inv  = 1.0f / (sqrtf(fmaxf(var, 0.0f)) + EPS_LN);
  f32x4 g0 = *(const f32x4*)(g + lane * 8);
  f32x4 g1 = *(const f32x4*)(g + lane * 8 + 4);
  f32x4 b0 = *(const f32x4*)(bt + lane * 8);
  f32x4 b1 = *(const f32x4*)(bt + lane * 8 + 4);
  bf16x8 ov;
  #pragma unroll
  for (int j = 0; j < 4; ++j) ov[j]     = (__bf16)((v0[j] - mean) * inv * g0[j] + b0[j]);
  #pragma unroll
  for (int j = 0; j < 4; ++j) ov[4 + j] = (__bf16)((v1[j] - mean) * inv * g1[j] + b1[j]);
  *(bf16x8*)(o + (size_t)row * CH + lane * 8) = ov;
}

__global__ void cast_bf16_kernel(const float* __restrict__ s, __bf16* __restrict__ d, int n) {
  int i = blockIdx.x * 256 + threadIdx.x;
  if (i < n) d[i] = (__bf16)s[i];
}

__global__ void bn_prep(const float* __restrict__ g, const float* __restrict__ bt,
                        const float* __restrict__ mean, const float* __restrict__ var,
                        float* __restrict__ scale, float* __restrict__ shift) {
  int c = blockIdx.x * blockDim.x + threadIdx.x;
  if (c >= CH) return;
  float s = g[c] * rsqrtf(var[c] + EPS_BN);
  scale[c] = s;
  shift[c] = bt[c] - mean[c] * s;
}

// ---------------------------------------------------------------------------
extern "C" void kernel_launch(void* const* d_in, const int* in_sizes, int n_in,
                              void* d_out, int out_size, void* d_ws, size_t ws_size,
                              hipStream_t stream) {
  const float* x      = (const float*)d_in[0];
  const float* ln1_g  = (const float*)d_in[1];
  const float* ln1_b  = (const float*)d_in[2];
  const float* wq     = (const float*)d_in[3];
  const float* bq     = (const float*)d_in[4];
  const float* wk     = (const float*)d_in[5];
  const float* bk     = (const float*)d_in[6];
  const float* wv     = (const float*)d_in[7];
  const float* bv     = (const float*)d_in[8];
  const float* swq    = (const float*)d_in[9];
  const float* sbq    = (const float*)d_in[10];
  const float* swk    = (const float*)d_in[11];
  const float* sbk    = (const float*)d_in[12];
  const float* swv    = (const float*)d_in[13];
  const float* sbv    = (const float*)d_in[14];
  const float* proj_w = (const float*)d_in[15];
  const float* bn_g   = (const float*)d_in[16];
  const float* bn_b   = (const float*)d_in[17];
  const float* bn_m   = (const float*)d_in[18];
  const float* bn_v   = (const float*)d_in[19];
  const float* ln2_g  = (const float*)d_in[20];
  const float* ln2_b  = (const float*)d_in[21];
  const float* w1     = (const float*)d_in[22];
  const float* b1     = (const float*)d_in[23];
  const float* w2     = (const float*)d_in[24];
  const float* b2     = (const float*)d_in[25];

  char* W = (char*)d_ws;
  const size_t SZB = 20480000;  // bytes per 16*512*625 f32 slot
  char* S0 = W;
  char* S1 = W + SZB;
  char* S2 = W + 2 * SZB;
  char* S3 = W + 3 * SZB;
  char* S4 = W + 4 * SZB;

  float*  xln   = (float*)S0;
  float*  qb    = (float*)S1;
  float*  kb    = (float*)S2;
  float*  vb    = (float*)S3;
  __bf16* qT    = (__bf16*)S0;
  __bf16* kTp   = qT + (size_t)BATCH * HEADS * NPIX * 64;
  __bf16* v16   = (__bf16*)d_out;
  float*  ab    = (float*)S4;
  __bf16* sq16  = (__bf16*)S1;
  __bf16* sk16  = (__bf16*)S2;
  float*  sv    = (float*)S3;
  __bf16* svT   = (__bf16*)S4;
  __bf16* Amat  = (__bf16*)S0;
  __bf16* pw16  = (__bf16*)(S0 + 10485760);
  __bf16* w116  = (__bf16*)(S0 + 10485760 + 524288);
  __bf16* w216  = (__bf16*)(S0 + 10485760 + 524288 + 2097152);
  float*  bnsc  = (float*)(S0 + 10485760 + 524288 + 2097152 + 2097152);
  float*  bnsh  = bnsc + CH;
  __bf16* xoutT = (__bf16*)S1;
  float*  x_nc  = (float*)S4;
  float*  y1_nc = (float*)S3;
  __bf16* y1ln  = (__bf16*)S0;
  __bf16* h1T   = (__bf16*)S1;   // spans S1+S2 (40.96 MB)
  float*  tmp_nc = (float*)S4;

  const size_t SZ = (size_t)BATCH * CH * NPIX;

  // 1. LN1: x -> xln [c][n]
  ln_kernel<<<dim3(3, BATCH), 256, 0, stream>>>(x, ln1_g, ln1_b, xln);
  // 2. q,k,v depthwise convs (25x25), f32
  dwconv3_kernel<<<(int)((SZ + 255) / 256), 256, 0, stream>>>(
      xln, wq, bq, wk, bk, wv, bv, qb, kb, vb, 25, 25);
  // 3. bf16 conversions for head attention
  qk_to_bf16T<<<dim3(10, BATCH * HEADS), 256, 0, stream>>>(qb, kb, qT, kTp);
  v_to_bf16<<<dim3(BATCH * CH), 256, 0, stream>>>(vb, v16);
  // 4. MFMA head attention -> ab [c][n] f32
  head_attn_mfma<<<dim3(10, HEADS, BATCH), 256, 0, stream>>>(qT, kTp, v16, ab);
  // 5. spe convs (5x125): sq16,sk16 bf16 [c][640] padded; sv f32 [c][625]
  dwconv_spe_kernel<<<(int)(((size_t)BATCH * CH * 640 + 255) / 256), 256, 0, stream>>>(
      ab, swq, sbq, swk, sbk, swv, sbv, sq16, sk16, sv);
  // 6. sv -> svT bf16 [b][625][512]
  transpose_bat<__bf16><<<dim3(10, 8, BATCH), 256, 0, stream>>>(sv, svT, CH, NPIX);
  // 7. weight casts + BN fold (into S0 upper region; qT/kT dead after step 4)
  cast_bf16_kernel<<<1024, 256, 0, stream>>>(proj_w, pw16, CH * CH);
  cast_bf16_kernel<<<4096, 256, 0, stream>>>(w1, w116, HIDD * CH);
  cast_bf16_kernel<<<4096, 256, 0, stream>>>(w2, w216, CH * HIDD);
  bn_prep<<<2, 256, 0, stream>>>(bn_g, bn_b, bn_m, bn_v, bnsc, bnsh);
  // 8. channel attention -> Amat bf16 [b][512][512]
  chan_attn_mfma<<<dim3(32, BATCH), 64, 0, stream>>>(sq16, sk16, Amat);
  // 9. G1: xoutT[b] = svT (625x512) . Amat^T -> bf16 [b][625][512]
  gemm_nt<0><<<dim3(8, 5, BATCH), 256, 0, stream>>>(
      svT, (long long)NPIX * CH, Amat, (long long)CH * CH,
      xoutT, (long long)NPIX * CH, NPIX, CH, CH,
      nullptr, nullptr, nullptr, 0);
  // 10. x -> x_nc f32 [b][625][512] (S4; svT dead after G1)
  transpose_bat<float><<<dim3(10, 8, BATCH), 256, 0, stream>>>(x, x_nc, CH, NPIX);
  // 11. G2: y1_nc = BN(xoutT . pw16^T) + x_nc   (f32, [10000][512])
  gemm_nt<1><<<dim3(8, 79, 1), 256, 0, stream>>>(
      xoutT, 0LL, pw16, 0LL, y1_nc, 0LL, BATCH * NPIX, CH, CH,
      bnsc, bnsh, x_nc, 0LL);
  // 12. LN2 (row-wise) -> y1ln bf16
  ln2_row_kernel<<<BATCH * NPIX / 4, 256, 0, stream>>>(y1_nc, ln2_g, ln2_b, y1ln);
  // 13. G3: h1T = gelu(y1ln . w116^T + b1)  bf16 [10000][2048]
  gemm_nt<2><<<dim3(32, 79, 1), 256, 0, stream>>>(
      y1ln, 0LL, w116, 0LL, h1T, 0LL, BATCH * NPIX, HIDD, CH,
      b1, nullptr, nullptr, 0LL);
  // 14. G4: tmp_nc = h1T . w216^T + b2 + y1_nc  (f32 [10000][512])
  gemm_nt<3><<<dim3(8, 79, 1), 256, 0, stream>>>(
      h1T, 0LL, w216, 0LL, tmp_nc, 0LL, BATCH * NPIX, CH, HIDD,
      b2, nullptr, y1_nc, 0LL);
  // 15. tmp_nc [b][625][512] -> d_out [b][512][625]
  transpose_bat<float><<<dim3(8, 10, BATCH), 256, 0, stream>>>(
      tmp_nc, (float*)d_out, NPIX, CH);
}

// Round 4
// 600.748 us; speedup vs baseline: 5.2848x; 1.0767x over previous
//
#include <hip/hip_runtime.h>
#include <math.h>

// Shapes
constexpr int BATCH = 16;
constexpr int CH    = 512;
constexpr int NPIX  = 625;   // 25*25 == 5*125
constexpr int HEADS = 8;
constexpr int HDIM  = 64;
constexpr int HIDD  = 2048;

constexpr float EPS_LN = 1e-5f;
constexpr float EPS_BN = 1e-5f;
constexpr float SCALE  = 0.125f;   // hd^-0.5, both attentions

typedef __bf16 bf16x8 __attribute__((ext_vector_type(8)));
typedef float  f32x4  __attribute__((ext_vector_type(4)));

static __device__ inline unsigned pack_bf16(float lo, float hi) {
  union { __bf16 h; unsigned short u; } a, b;
  a.h = (__bf16)lo; b.h = (__bf16)hi;
  return ((unsigned)b.u << 16) | (unsigned)a.u;
}

// ---------------------------------------------------------------------------
// Channel LayerNorm v2: block = 64 positions x 4 channel-split waves.
// grid (10, BATCH). Partial sums combined in LDS.
// ---------------------------------------------------------------------------
__global__ __launch_bounds__(256) void ln_kernel2(
    const float* __restrict__ x, const float* __restrict__ g,
    const float* __restrict__ bt, float* __restrict__ y) {
  __shared__ float ps[4][64];
  __shared__ float pss[4][64];
  int lane = threadIdx.x & 63;
  int w    = threadIdx.x >> 6;
  int b    = blockIdx.y;
  int i    = blockIdx.x * 64 + lane;
  int ic   = i < NPIX ? i : NPIX - 1;
  const float* xb = x + (size_t)b * CH * NPIX + ic;
  float s = 0.f, ss = 0.f;
  #pragma unroll 4
  for (int c = w * 128; c < w * 128 + 128; ++c) {
    float v = xb[(size_t)c * NPIX];
    s += v; ss += v * v;
  }
  ps[w][lane] = s; pss[w][lane] = ss;
  __syncthreads();
  float st  = ps[0][lane] + ps[1][lane] + ps[2][lane] + ps[3][lane];
  float sst = pss[0][lane] + pss[1][lane] + pss[2][lane] + pss[3][lane];
  float mean = st * (1.0f / CH);
  float var  = sst * (1.0f / CH) - mean * mean;
  float inv  = 1.0f / (sqrtf(fmaxf(var, 0.0f)) + EPS_LN);
  if (i >= NPIX) return;
  float* yb = y + (size_t)b * CH * NPIX + i;
  #pragma unroll 4
  for (int c = w * 128; c < w * 128 + 128; ++c) {
    float v = xb[(size_t)c * NPIX];
    yb[(size_t)c * NPIX] = (v - mean) * inv * g[c] + bt[c];
  }
}

// ---------------------------------------------------------------------------
// First depthwise conv (25x25): three convs in one pass, f32 out. (unchanged)
// ---------------------------------------------------------------------------
__global__ void dwconv3_kernel(const float* __restrict__ src,
    const float* __restrict__ w0, const float* __restrict__ b0,
    const float* __restrict__ w1, const float* __restrict__ b1,
    const float* __restrict__ w2, const float* __restrict__ b2,
    float* __restrict__ d0, float* __restrict__ d1, float* __restrict__ d2,
    int Hc, int Wc) {
  size_t idx = (size_t)blockIdx.x * blockDim.x + threadIdx.x;
  size_t total = (size_t)BATCH * CH * Hc * Wc;
  if (idx >= total) return;
  int wp = (int)(idx % Wc);
  int hp = (int)((idx / Wc) % Hc);
  int c  = (int)((idx / ((size_t)Wc * Hc)) % CH);
  const float* f0 = w0 + c * 9;
  const float* f1 = w1 + c * 9;
  const float* f2 = w2 + c * 9;
  float a0 = 0.f, a1 = 0.f, a2 = 0.f;
  #pragma unroll
  for (int kh = -1; kh <= 1; ++kh) {
    int h2 = hp + kh; if (h2 < 0 || h2 >= Hc) continue;
    #pragma unroll
    for (int kw = -1; kw <= 1; ++kw) {
      int w2p = wp + kw; if (w2p < 0 || w2p >= Wc) continue;
      float v = src[idx + (size_t)kh * Wc + kw];
      int wi = (kh + 1) * 3 + (kw + 1);
      a0 += v * f0[wi]; a1 += v * f1[wi]; a2 += v * f2[wi];
    }
  }
  d0[idx] = a0 + b0[c];
  d1[idx] = a1 + b1[c];
  d2[idx] = a2 + b2[c];
}

// ---------------------------------------------------------------------------
// spe depthwise conv (5x125): q,k -> bf16 [c][640] padded; v -> f32. (unchanged)
// ---------------------------------------------------------------------------
__global__ void dwconv_spe_kernel(const float* __restrict__ src,
    const float* __restrict__ w0, const float* __restrict__ b0,
    const float* __restrict__ w1, const float* __restrict__ b1,
    const float* __restrict__ w2, const float* __restrict__ b2,
    __bf16* __restrict__ q16, __bf16* __restrict__ k16, float* __restrict__ v) {
  size_t idx = (size_t)blockIdx.x * blockDim.x + threadIdx.x;
  if (idx >= (size_t)BATCH * CH * 640) return;
  int n = (int)(idx % 640);
  int c = (int)((idx / 640) % CH);
  int b = (int)(idx / ((size_t)640 * CH));
  if (n >= NPIX) { q16[idx] = (__bf16)0.f; k16[idx] = (__bf16)0.f; return; }
  int hp = n / 125, wp = n % 125;
  size_t base = ((size_t)b * CH + c) * NPIX;
  const float* f0 = w0 + c * 9;
  const float* f1 = w1 + c * 9;
  const float* f2 = w2 + c * 9;
  float a0 = 0.f, a1 = 0.f, a2 = 0.f;
  #pragma unroll
  for (int kh = -1; kh <= 1; ++kh) {
    int h2 = hp + kh; if (h2 < 0 || h2 >= 5) continue;
    #pragma unroll
    for (int kw = -1; kw <= 1; ++kw) {
      int w2p = wp + kw; if (w2p < 0 || w2p >= 125) continue;
      float vv = src[base + h2 * 125 + w2p];
      int wi = (kh + 1) * 3 + (kw + 1);
      a0 += vv * f0[wi]; a1 += vv * f1[wi]; a2 += vv * f2[wi];
    }
  }
  q16[idx] = (__bf16)(a0 + b0[c]);
  k16[idx] = (__bf16)(a1 + b1[c]);
  v[base + n] = a2 + b2[c];
}

// ---------------------------------------------------------------------------
// Transpose+cast q,k: [b][h*64+d][n] f32 -> [bh][n][64] bf16. (unchanged)
// ---------------------------------------------------------------------------
__global__ __launch_bounds__(256) void qk_to_bf16T(
    const float* __restrict__ q, const float* __restrict__ k,
    __bf16* __restrict__ qT, __bf16* __restrict__ kT) {
  __shared__ __bf16 tq[64][65];
  __shared__ __bf16 tk[64][65];
  int bh = blockIdx.y;
  int n0 = blockIdx.x * 64;
  int b = bh >> 3, h = bh & 7;
  const float* qb = q + (size_t)(b * CH + h * HDIM) * NPIX;
  const float* kb = k + (size_t)(b * CH + h * HDIM) * NPIX;
  #pragma unroll
  for (int it = 0; it < 16; ++it) {
    int idx = threadIdx.x + it * 256;
    int d = idx >> 6, n = idx & 63;
    int nn = n0 + n;
    float qv = (nn < NPIX) ? qb[(size_t)d * NPIX + nn] : 0.f;
    float kv = (nn < NPIX) ? kb[(size_t)d * NPIX + nn] : 0.f;
    tq[n][d] = (__bf16)qv;
    tk[n][d] = (__bf16)kv;
  }
  __syncthreads();
  size_t obase = (size_t)bh * NPIX;
  #pragma unroll
  for (int it = 0; it < 16; ++it) {
    int idx = threadIdx.x + it * 256;
    int n = idx >> 6, d = idx & 63;
    int nn = n0 + n;
    if (nn < NPIX) {
      qT[(obase + nn) * 64 + d] = tq[n][d];
      kT[(obase + nn) * 64 + d] = tk[n][d];
    }
  }
}

// v: [c][625] f32 -> [c][640] bf16. (unchanged)
__global__ void v_to_bf16(const float* __restrict__ v, __bf16* __restrict__ v16) {
  int row = blockIdx.x;
  const float* src = v + (size_t)row * NPIX;
  __bf16* dst = v16 + (size_t)row * 640;
  for (int n = threadIdx.x; n < NPIX; n += 256) dst[n] = (__bf16)src[n];
}

// ---------------------------------------------------------------------------
// MFMA head attention v2: full-S single pass, 1 wave per 16 q-rows.
// grid (40, HEADS, BATCH), 64 threads. S held in 40 f32x4 frags; softmax once;
// P normalized in-register, packed to XOR-swizzled LDS via paired-col b32
// writes; PV reads b128 A-frags; output staged in (reused) LDS for coalesced
// stores into [b][h*64+d][n] f32.
// ---------------------------------------------------------------------------
__global__ __launch_bounds__(64) void head_attn_mfma2(
    const __bf16* __restrict__ qT, const __bf16* __restrict__ kT,
    const __bf16* __restrict__ vB, float* __restrict__ out) {
  __shared__ __align__(16) union SmT {
    unsigned char p[16 * 1280];   // P: 16 rows x 640 cols bf16, XOR-swizzled
    float ostage[64][17];         // output transpose staging (reused)
  } sm;
  int lane = threadIdx.x & 63;
  int g = lane >> 4, li = lane & 15;
  int h = blockIdx.y, b = blockIdx.z;
  int bh = b * HEADS + h;
  int i0 = blockIdx.x * 16;
  const __bf16* Qb = qT + (size_t)bh * NPIX * 64;
  const __bf16* Kb = kT + (size_t)bh * NPIX * 64;
  const __bf16* Vb = vB + (size_t)(b * CH + h * HDIM) * 640;

  // Q A-frags: lane holds Q[i0+li][8g+j (+32)]
  bf16x8 aq0, aq1;
  {
    int qr = i0 + li; if (qr > NPIX - 1) qr = NPIX - 1;
    const __bf16* qp = Qb + (size_t)qr * 64 + 8 * g;
    aq0 = *(const bf16x8*)(qp);
    aq1 = *(const bf16x8*)(qp + 32);
  }

  // ---- S = Q @ K^T : 40 column-frags, all independent ----
  f32x4 s[40];
  #pragma unroll
  for (int cf = 0; cf < 40; ++cf) {
    int kc = cf * 16 + li;
    int kcl = kc > NPIX - 1 ? NPIX - 1 : kc;
    const __bf16* kp = Kb + (size_t)kcl * 64 + 8 * g;
    bf16x8 bk0 = *(const bf16x8*)(kp);
    bf16x8 bk1 = *(const bf16x8*)(kp + 32);
    f32x4 acc = (f32x4){0.f, 0.f, 0.f, 0.f};
    acc = __builtin_amdgcn_mfma_f32_16x16x32_bf16(aq0, bk0, acc, 0, 0, 0);
    acc = __builtin_amdgcn_mfma_f32_16x16x32_bf16(aq1, bk1, acc, 0, 0, 0);
    s[cf] = acc * SCALE;
  }
  // mask invalid key columns (cf=39: cols 624+li, valid only li==0)
  if (li > 0) {
    s[39][0] = -1e30f; s[39][1] = -1e30f; s[39][2] = -1e30f; s[39][3] = -1e30f;
  }

  // ---- softmax (once), normalize P in-register ----
  #pragma unroll
  for (int r = 0; r < 4; ++r) {
    float mx = -1e30f;
    #pragma unroll
    for (int cf = 0; cf < 40; ++cf) mx = fmaxf(mx, s[cf][r]);
    mx = fmaxf(mx, __shfl_xor(mx, 1));
    mx = fmaxf(mx, __shfl_xor(mx, 2));
    mx = fmaxf(mx, __shfl_xor(mx, 4));
    mx = fmaxf(mx, __shfl_xor(mx, 8));
    float sum = 0.f;
    #pragma unroll
    for (int cf = 0; cf < 40; ++cf) {
      float p = __expf(s[cf][r] - mx);
      s[cf][r] = p;
      sum += p;
    }
    sum += __shfl_xor(sum, 1);
    sum += __shfl_xor(sum, 2);
    sum += __shfl_xor(sum, 4);
    sum += __shfl_xor(sum, 8);
    float inv = 1.0f / sum;
    #pragma unroll
    for (int cf = 0; cf < 40; ++cf) s[cf][r] *= inv;
  }

  // ---- P -> LDS: paired-column packed b32 writes, XOR swizzle ----
  // even li handles cf0's col pair (li, li+1); odd li handles cf1's (li-1, li)
  #pragma unroll
  for (int cfp = 0; cfp < 20; ++cfp) {
    int cf0 = 2 * cfp, cf1 = cf0 + 1;
    #pragma unroll
    for (int r = 0; r < 4; ++r) {
      float v0 = s[cf0][r], v1 = s[cf1][r];
      float t0 = __shfl_xor(v0, 1);
      float t1 = __shfl_xor(v1, 1);
      bool even = (li & 1) == 0;
      float lo = even ? v0 : t1;
      float hi = even ? t0 : v1;
      int col_w = even ? (cf0 * 16 + li) : (cf1 * 16 + li - 1);
      int row = 4 * g + r;
      int off = (row * 1280 + col_w * 2) ^ ((row & 7) << 4);
      *(unsigned*)(&sm.p[off]) = pack_bf16(lo, hi);
    }
  }

  // ---- O = P @ V ----
  f32x4 o[4];
  #pragma unroll
  for (int dg = 0; dg < 4; ++dg) o[dg] = (f32x4){0.f, 0.f, 0.f, 0.f};
  #pragma unroll
  for (int ks = 0; ks < 20; ++ks) {
    int offr = (li * 1280 + ks * 64 + 16 * g) ^ ((li & 7) << 4);
    bf16x8 pa = *(const bf16x8*)(&sm.p[offr]);
    const __bf16* vp = Vb + (size_t)li * 640 + ks * 32 + 8 * g;
    #pragma unroll
    for (int dg = 0; dg < 4; ++dg) {
      bf16x8 bv = *(const bf16x8*)(vp + (size_t)dg * 16 * 640);
      o[dg] = __builtin_amdgcn_mfma_f32_16x16x32_bf16(pa, bv, o[dg], 0, 0, 0);
    }
  }

  // ---- epilogue: transpose via LDS (reuse P region), coalesced store ----
  __syncthreads();
  #pragma unroll
  for (int dg = 0; dg < 4; ++dg) {
    #pragma unroll
    for (int r = 0; r < 4; ++r)
      sm.ostage[dg * 16 + li][4 * g + r] = o[dg][r];
  }
  __syncthreads();
  size_t cbase = (size_t)(b * CH + h * HDIM);
  int n = i0 + li;
  if (n < NPIX) {
    #pragma unroll
    for (int dd = 0; dd < 16; ++dd) {
      int d = dd * 4 + g;
      out[(cbase + d) * NPIX + n] = sm.ostage[d][li];
    }
  }
}

// ---------------------------------------------------------------------------
// MFMA channel attention (unchanged, verified round 2).
// ---------------------------------------------------------------------------
__global__ __launch_bounds__(64) void chan_attn_mfma(
    const __bf16* __restrict__ sq, const __bf16* __restrict__ sk,
    __bf16* __restrict__ Am) {
  int lane = threadIdx.x & 63;
  int g = lane >> 4, li = lane & 15;
  int b = blockIdx.y;
  int cq0 = blockIdx.x * 16;
  const __bf16* qrow  = sq + ((size_t)b * CH + cq0 + li) * 640 + 8 * g;
  const __bf16* kbase = sk + ((size_t)b * CH + li) * 640 + 8 * g;
  f32x4 acc[32];
  #pragma unroll
  for (int i = 0; i < 32; ++i) acc[i] = (f32x4){0.f, 0.f, 0.f, 0.f};
  for (int ks = 0; ks < 20; ++ks) {
    bf16x8 af = *(const bf16x8*)(qrow + ks * 32);
    #pragma unroll
    for (int cf = 0; cf < 32; ++cf) {
      bf16x8 bfr = *(const bf16x8*)(kbase + (size_t)cf * 16 * 640 + ks * 32);
      acc[cf] = __builtin_amdgcn_mfma_f32_16x16x32_bf16(af, bfr, acc[cf], 0, 0, 0);
    }
  }
  #pragma unroll
  for (int i = 0; i < 32; ++i) acc[i] = acc[i] * SCALE;
  __bf16* Ab = Am + ((size_t)b * CH + cq0) * CH;
  #pragma unroll
  for (int r = 0; r < 4; ++r) {
    float mx = -1e30f;
    #pragma unroll
    for (int cf = 0; cf < 32; ++cf) mx = fmaxf(mx, acc[cf][r]);
    mx = fmaxf(mx, __shfl_xor(mx, 1));
    mx = fmaxf(mx, __shfl_xor(mx, 2));
    mx = fmaxf(mx, __shfl_xor(mx, 4));
    mx = fmaxf(mx, __shfl_xor(mx, 8));
    float sum = 0.f;
    #pragma unroll
    for (int cf = 0; cf < 32; ++cf) {
      float p = __expf(acc[cf][r] - mx);
      acc[cf][r] = p;
      sum += p;
    }
    sum += __shfl_xor(sum, 1);
    sum += __shfl_xor(sum, 2);
    sum += __shfl_xor(sum, 4);
    sum += __shfl_xor(sum, 8);
    float inv = 1.0f / sum;
    #pragma unroll
    for (int cf = 0; cf < 32; ++cf)
      Ab[(size_t)(4 * g + r) * CH + cf * 16 + li] = (__bf16)(acc[cf][r] * inv);
  }
}

// ---------------------------------------------------------------------------
// NT bf16 MFMA GEMM (unchanged, verified round 2).
// ---------------------------------------------------------------------------
template <int EPI>
__global__ __launch_bounds__(256) void gemm_nt(
    const __bf16* __restrict__ A, long long aBatch,
    const __bf16* __restrict__ B, long long bBatch,
    void* __restrict__ Cout, long long cBatch,
    int M, int N, int K,
    const float* __restrict__ p0, const float* __restrict__ p1,
    const float* __restrict__ res, long long resBatch) {
  __shared__ __align__(16) union {
    struct { unsigned char As[128 * 128]; unsigned char Bs[64 * 128]; } s;
    float Ce[4][64][17];
  } u;
  int t = threadIdx.x;
  int w = t >> 6, lane = t & 63, g = lane >> 4, li = lane & 15;
  int wm = w & 1, wn = w >> 1;
  int n0 = blockIdx.x * 64, m0 = blockIdx.y * 128, b = blockIdx.z;
  const __bf16* Ab = A + (size_t)b * aBatch;
  const __bf16* Bb = B + (size_t)b * bBatch;
  f32x4 acc[4][2];
  #pragma unroll
  for (int i = 0; i < 4; ++i)
    #pragma unroll
    for (int j = 0; j < 2; ++j) acc[i][j] = (f32x4){0.f, 0.f, 0.f, 0.f};

  for (int k0 = 0; k0 < K; k0 += 64) {
    bf16x8 ra[4], rb[2];
    #pragma unroll
    for (int i = 0; i < 4; ++i) {
      int e = t + i * 256;
      int row = e >> 3, cc = e & 7;
      int ar = m0 + row; ar = ar < M ? ar : M - 1;
      ra[i] = *(const bf16x8*)(Ab + (size_t)ar * K + k0 + cc * 8);
    }
    #pragma unroll
    for (int i = 0; i < 2; ++i) {
      int e = t + i * 256;
      int row = e >> 3, cc = e & 7;
      rb[i] = *(const bf16x8*)(Bb + (size_t)(n0 + row) * K + k0 + cc * 8);
    }
    __syncthreads();
    #pragma unroll
    for (int i = 0; i < 4; ++i) {
      int e = t + i * 256; int row = e >> 3, cc = e & 7;
      int off = (row * 128 + cc * 16) ^ ((row & 7) << 4);
      *(bf16x8*)(&u.s.As[off]) = ra[i];
    }
    #pragma unroll
    for (int i = 0; i < 2; ++i) {
      int e = t + i * 256; int row = e >> 3, cc = e & 7;
      int off = (row * 128 + cc * 16) ^ ((row & 7) << 4);
      *(bf16x8*)(&u.s.Bs[off]) = rb[i];
    }
    __syncthreads();
    #pragma unroll
    for (int ks = 0; ks < 2; ++ks) {
      bf16x8 af[4], bfr[2];
      #pragma unroll
      for (int mf = 0; mf < 4; ++mf) {
        int row = wm * 64 + mf * 16 + li;
        int off = (row * 128 + ks * 64 + g * 16) ^ ((row & 7) << 4);
        af[mf] = *(const bf16x8*)(&u.s.As[off]);
      }
      #pragma unroll
      for (int nf = 0; nf < 2; ++nf) {
        int row = wn * 32 + nf * 16 + li;
        int off = (row * 128 + ks * 64 + g * 16) ^ ((row & 7) << 4);
        bfr[nf] = *(const bf16x8*)(&u.s.Bs[off]);
      }
      #pragma unroll
      for (int mf = 0; mf < 4; ++mf)
        #pragma unroll
        for (int nf = 0; nf < 2; ++nf)
          acc[mf][nf] = __builtin_amdgcn_mfma_f32_16x16x32_bf16(
              af[mf], bfr[nf], acc[mf][nf], 0, 0, 0);
    }
    __syncthreads();
  }

  #pragma unroll
  for (int p = 0; p < 2; ++p) {
    __syncthreads();
    #pragma unroll
    for (int mf = 0; mf < 4; ++mf) {
      #pragma unroll
      for (int r = 0; r < 4; ++r)
        u.Ce[w][mf * 16 + 4 * g + r][li] = acc[mf][p][r];
    }
    __syncthreads();
    int m = m0 + wm * 64 + lane;
    int colb = n0 + wn * 32 + p * 16;
    if (m < M) {
      float vv[16];
      #pragma unroll
      for (int c = 0; c < 16; ++c) vv[c] = u.Ce[w][lane][c];
      if (EPI == 0) {
        __bf16* Cb = (__bf16*)Cout + (size_t)b * cBatch + (size_t)m * N + colb;
        bf16x8 o0, o1;
        #pragma unroll
        for (int j = 0; j < 8; ++j) { o0[j] = (__bf16)vv[j]; o1[j] = (__bf16)vv[8 + j]; }
        *(bf16x8*)(Cb) = o0;
        *(bf16x8*)(Cb + 8) = o1;
      } else if (EPI == 1) {
        float* Cf = (float*)Cout + (size_t)b * cBatch + (size_t)m * N + colb;
        const float* rp = res + (size_t)b * resBatch + (size_t)m * N + colb;
        #pragma unroll
        for (int c = 0; c < 16; ++c)
          vv[c] = vv[c] * p0[colb + c] + p1[colb + c] + rp[c];
        #pragma unroll
        for (int c4 = 0; c4 < 4; ++c4)
          *(f32x4*)(Cf + c4 * 4) = (f32x4){vv[c4*4], vv[c4*4+1], vv[c4*4+2], vv[c4*4+3]};
      } else if (EPI == 2) {
        __bf16* Cb = (__bf16*)Cout + (size_t)b * cBatch + (size_t)m * N + colb;
        #pragma unroll
        for (int c = 0; c < 16; ++c) {
          float xg = vv[c] + p0[colb + c];
          vv[c] = 0.5f * xg * (1.0f + erff(xg * 0.70710678118654752f));
        }
        bf16x8 o0, o1;
        #pragma unroll
        for (int j = 0; j < 8; ++j) { o0[j] = (__bf16)vv[j]; o1[j] = (__bf16)vv[8 + j]; }
        *(bf16x8*)(Cb) = o0;
        *(bf16x8*)(Cb + 8) = o1;
      } else {
        float* Cf = (float*)Cout + (size_t)b * cBatch + (size_t)m * N + colb;
        const float* rp = res + (size_t)b * resBatch + (size_t)m * N + colb;
        #pragma unroll
        for (int c = 0; c < 16; ++c)
          vv[c] = vv[c] + p0[colb + c] + rp[c];
        #pragma unroll
        for (int c4 = 0; c4 < 4; ++c4)
          *(f32x4*)(Cf + c4 * 4) = (f32x4){vv[c4*4], vv[c4*4+1], vv[c4*4+2], vv[c4*4+3]};
      }
    }
  }
}

// ---------------------------------------------------------------------------
// Batched tiled transpose (unchanged).
// ---------------------------------------------------------------------------
template <typename TO>
__global__ __launch_bounds__(256) void transpose_bat(
    const float* __restrict__ in, TO* __restrict__ out, int R, int Cc) {
  __shared__ float tile[64][65];
  int b = blockIdx.z;
  int c0 = blockIdx.x * 64, r0 = blockIdx.y * 64;
  const float* ib = in + (size_t)b * R * Cc;
  TO* ob = out + (size_t)b * R * Cc;
  for (int e = threadIdx.x; e < 4096; e += 256) {
    int rr = e >> 6, cc = e & 63;
    int r = r0 + rr, c = c0 + cc;
    tile[rr][cc] = (r < R && c < Cc) ? ib[(size_t)r * Cc + c] : 0.f;
  }
  __syncthreads();
  for (int e = threadIdx.x; e < 4096; e += 256) {
    int cc = e >> 6, rr = e & 63;
    int r = r0 + rr, c = c0 + cc;
    if (r < R && c < Cc) ob[(size_t)c * R + r] = (TO)tile[rr][cc];
  }
}

// ---------------------------------------------------------------------------
// Row LayerNorm (unchanged).
// ---------------------------------------------------------------------------
__global__ __launch_bounds__(256) void ln2_row_kernel(
    const float* __restrict__ y, const float* __restrict__ g,
    const float* __restrict__ bt, __bf16* __restrict__ o) {
  int row = blockIdx.x * 4 + (threadIdx.x >> 6);
  int lane = threadIdx.x & 63;
  const float* yr = y + (size_t)row * CH + lane * 8;
  f32x4 v0 = *(const f32x4*)(yr);
  f32x4 v1 = *(const f32x4*)(yr + 4);
  float s = v0[0]+v0[1]+v0[2]+v0[3]+v1[0]+v1[1]+v1[2]+v1[3];
  float ss = v0[0]*v0[0]+v0[1]*v0[1]+v0[2]*v0[2]+v0[3]*v0[3]
           + v1[0]*v1[0]+v1[1]*v1[1]+v1[2]*v1[2]+v1[3]*v1[3];
  #pragma unroll
  for (int off = 32; off > 0; off >>= 1) {
    s  += __shfl_xor(s, off);
    ss += __shfl_xor(ss, off);
  }
  float mean = s * (1.0f / CH);
  float var  = ss * (1.0f / CH) - mean * mean;
  float inv  = 1.0f / (sqrtf(fmaxf(var, 0.0f)) + EPS_LN);
  f32x4 g0 = *(const f32x4*)(g + lane * 8);
  f32x4 g1 = *(const f32x4*)(g + lane * 8 + 4);
  f32x4 b0 = *(const f32x4*)(bt + lane * 8);
  f32x4 b1 = *(const f32x4*)(bt + lane * 8 + 4);
  bf16x8 ov;
  #pragma unroll
  for (int j = 0; j < 4; ++j) ov[j]     = (__bf16)((v0[j] - mean) * inv * g0[j] + b0[j]);
  #pragma unroll
  for (int j = 0; j < 4; ++j) ov[4 + j] = (__bf16)((v1[j] - mean) * inv * g1[j] + b1[j]);
  *(bf16x8*)(o + (size_t)row * CH + lane * 8) = ov;
}

__global__ void cast_bf16_kernel(const float* __restrict__ s, __bf16* __restrict__ d, int n) {
  int i = blockIdx.x * 256 + threadIdx.x;
  if (i < n) d[i] = (__bf16)s[i];
}

__global__ void bn_prep(const float* __restrict__ g, const float* __restrict__ bt,
                        const float* __restrict__ mean, const float* __restrict__ var,
                        float* __restrict__ scale, float* __restrict__ shift) {
  int c = blockIdx.x * blockDim.x + threadIdx.x;
  if (c >= CH) return;
  float s = g[c] * rsqrtf(var[c] + EPS_BN);
  scale[c] = s;
  shift[c] = bt[c] - mean[c] * s;
}

// ---------------------------------------------------------------------------
extern "C" void kernel_launch(void* const* d_in, const int* in_sizes, int n_in,
                              void* d_out, int out_size, void* d_ws, size_t ws_size,
                              hipStream_t stream) {
  const float* x      = (const float*)d_in[0];
  const float* ln1_g  = (const float*)d_in[1];
  const float* ln1_b  = (const float*)d_in[2];
  const float* wq     = (const float*)d_in[3];
  const float* bq     = (const float*)d_in[4];
  const float* wk     = (const float*)d_in[5];
  const float* bk     = (const float*)d_in[6];
  const float* wv     = (const float*)d_in[7];
  const float* bv     = (const float*)d_in[8];
  const float* swq    = (const float*)d_in[9];
  const float* sbq    = (const float*)d_in[10];
  const float* swk    = (const float*)d_in[11];
  const float* sbk    = (const float*)d_in[12];
  const float* swv    = (const float*)d_in[13];
  const float* sbv    = (const float*)d_in[14];
  const float* proj_w = (const float*)d_in[15];
  const float* bn_g   = (const float*)d_in[16];
  const float* bn_b   = (const float*)d_in[17];
  const float* bn_m   = (const float*)d_in[18];
  const float* bn_v   = (const float*)d_in[19];
  const float* ln2_g  = (const float*)d_in[20];
  const float* ln2_b  = (const float*)d_in[21];
  const float* w1     = (const float*)d_in[22];
  const float* b1     = (const float*)d_in[23];
  const float* w2     = (const float*)d_in[24];
  const float* b2     = (const float*)d_in[25];

  char* W = (char*)d_ws;
  const size_t SZB = 20480000;  // bytes per 16*512*625 f32 slot
  char* S0 = W;
  char* S1 = W + SZB;
  char* S2 = W + 2 * SZB;
  char* S3 = W + 3 * SZB;
  char* S4 = W + 4 * SZB;

  float*  xln   = (float*)S0;
  float*  qb    = (float*)S1;
  float*  kb    = (float*)S2;
  float*  vb    = (float*)S3;
  __bf16* qT    = (__bf16*)S0;
  __bf16* kTp   = qT + (size_t)BATCH * HEADS * NPIX * 64;
  __bf16* v16   = (__bf16*)d_out;
  float*  ab    = (float*)S4;
  __bf16* sq16  = (__bf16*)S1;
  __bf16* sk16  = (__bf16*)S2;
  float*  sv    = (float*)S3;
  __bf16* svT   = (__bf16*)S4;
  __bf16* Amat  = (__bf16*)S0;
  __bf16* pw16  = (__bf16*)(S0 + 10485760);
  __bf16* w116  = (__bf16*)(S0 + 10485760 + 524288);
  __bf16* w216  = (__bf16*)(S0 + 10485760 + 524288 + 2097152);
  float*  bnsc  = (float*)(S0 + 10485760 + 524288 + 2097152 + 2097152);
  float*  bnsh  = bnsc + CH;
  __bf16* xoutT = (__bf16*)S1;
  float*  x_nc  = (float*)S4;
  float*  y1_nc = (float*)S3;
  __bf16* y1ln  = (__bf16*)S0;
  __bf16* h1T   = (__bf16*)S1;   // spans S1+S2
  float*  tmp_nc = (float*)S4;

  const size_t SZ = (size_t)BATCH * CH * NPIX;

  // 1. LN1: x -> xln [c][n]
  ln_kernel2<<<dim3(10, BATCH), 256, 0, stream>>>(x, ln1_g, ln1_b, xln);
  // 2. q,k,v depthwise convs (25x25), f32
  dwconv3_kernel<<<(int)((SZ + 255) / 256), 256, 0, stream>>>(
      xln, wq, bq, wk, bk, wv, bv, qb, kb, vb, 25, 25);
  // 3. bf16 conversions for head attention
  qk_to_bf16T<<<dim3(10, BATCH * HEADS), 256, 0, stream>>>(qb, kb, qT, kTp);
  v_to_bf16<<<dim3(BATCH * CH), 256, 0, stream>>>(vb, v16);
  // 4. MFMA head attention v2 -> ab [c][n] f32
  head_attn_mfma2<<<dim3(40, HEADS, BATCH), 64, 0, stream>>>(qT, kTp, v16, ab);
  // 5. spe convs (5x125): sq16,sk16 bf16 [c][640]; sv f32 [c][625]
  dwconv_spe_kernel<<<(int)(((size_t)BATCH * CH * 640 + 255) / 256), 256, 0, stream>>>(
      ab, swq, sbq, swk, sbk, swv, sbv, sq16, sk16, sv);
  // 6. sv -> svT bf16 [b][625][512]
  transpose_bat<__bf16><<<dim3(10, 8, BATCH), 256, 0, stream>>>(sv, svT, CH, NPIX);
  // 7. weight casts + BN fold
  cast_bf16_kernel<<<1024, 256, 0, stream>>>(proj_w, pw16, CH * CH);
  cast_bf16_kernel<<<4096, 256, 0, stream>>>(w1, w116, HIDD * CH);
  cast_bf16_kernel<<<4096, 256, 0, stream>>>(w2, w216, CH * HIDD);
  bn_prep<<<2, 256, 0, stream>>>(bn_g, bn_b, bn_m, bn_v, bnsc, bnsh);
  // 8. channel attention -> Amat bf16 [b][512][512]
  chan_attn_mfma<<<dim3(32, BATCH), 64, 0, stream>>>(sq16, sk16, Amat);
  // 9. G1: xoutT[b] = svT (625x512) . Amat^T -> bf16 [b][625][512]
  gemm_nt<0><<<dim3(8, 5, BATCH), 256, 0, stream>>>(
      svT, (long long)NPIX * CH, Amat, (long long)CH * CH,
      xoutT, (long long)NPIX * CH, NPIX, CH, CH,
      nullptr, nullptr, nullptr, 0);
  // 10. x -> x_nc f32 [b][625][512]
  transpose_bat<float><<<dim3(10, 8, BATCH), 256, 0, stream>>>(x, x_nc, CH, NPIX);
  // 11. G2: y1_nc = BN(xoutT . pw16^T) + x_nc   (f32, [10000][512])
  gemm_nt<1><<<dim3(8, 79, 1), 256, 0, stream>>>(
      xoutT, 0LL, pw16, 0LL, y1_nc, 0LL, BATCH * NPIX, CH, CH,
      bnsc, bnsh, x_nc, 0LL);
  // 12. LN2 (row-wise) -> y1ln bf16
  ln2_row_kernel<<<BATCH * NPIX / 4, 256, 0, stream>>>(y1_nc, ln2_g, ln2_b, y1ln);
  // 13. G3: h1T = gelu(y1ln . w116^T + b1)  bf16 [10000][2048]
  gemm_nt<2><<<dim3(32, 79, 1), 256, 0, stream>>>(
      y1ln, 0LL, w116, 0LL, h1T, 0LL, BATCH * NPIX, HIDD, CH,
      b1, nullptr, nullptr, 0LL);
  // 14. G4: tmp_nc = h1T . w216^T + b2 + y1_nc  (f32 [10000][512])
  gemm_nt<3><<<dim3(8, 79, 1), 256, 0, stream>>>(
      h1T, 0LL, w216, 0LL, tmp_nc, 0LL, BATCH * NPIX, CH, HIDD,
      b2, nullptr, y1_nc, 0LL);
  // 15. tmp_nc [b][625][512] -> d_out [b][512][625]
  transpose_bat<float><<<dim3(8, 10, BATCH), 256, 0, stream>>>(
      tmp_nc, (float*)d_out, NPIX, CH);
}

// Round 6
// 592.570 us; speedup vs baseline: 5.3577x; 1.0138x over previous
//
#include <hip/hip_runtime.h>
#include <math.h>

// Shapes
constexpr int BATCH = 16;
constexpr int CH    = 512;
constexpr int NPIX  = 625;   // 25*25 == 5*125
constexpr int HEADS = 8;
constexpr int HDIM  = 64;
constexpr int HIDD  = 2048;

constexpr float EPS_LN = 1e-5f;
constexpr float EPS_BN = 1e-5f;
constexpr float SCALE  = 0.125f;   // hd^-0.5, both attentions

typedef __bf16 bf16x8 __attribute__((ext_vector_type(8)));
typedef float  f32x4  __attribute__((ext_vector_type(4)));

// ---------------------------------------------------------------------------
// Channel LayerNorm v2 (unchanged from round 3).
// ---------------------------------------------------------------------------
__global__ __launch_bounds__(256) void ln_kernel2(
    const float* __restrict__ x, const float* __restrict__ g,
    const float* __restrict__ bt, float* __restrict__ y) {
  __shared__ float ps[4][64];
  __shared__ float pss[4][64];
  int lane = threadIdx.x & 63;
  int w    = threadIdx.x >> 6;
  int b    = blockIdx.y;
  int i    = blockIdx.x * 64 + lane;
  int ic   = i < NPIX ? i : NPIX - 1;
  const float* xb = x + (size_t)b * CH * NPIX + ic;
  float s = 0.f, ss = 0.f;
  #pragma unroll 4
  for (int c = w * 128; c < w * 128 + 128; ++c) {
    float v = xb[(size_t)c * NPIX];
    s += v; ss += v * v;
  }
  ps[w][lane] = s; pss[w][lane] = ss;
  __syncthreads();
  float st  = ps[0][lane] + ps[1][lane] + ps[2][lane] + ps[3][lane];
  float sst = pss[0][lane] + pss[1][lane] + pss[2][lane] + pss[3][lane];
  float mean = st * (1.0f / CH);
  float var  = sst * (1.0f / CH) - mean * mean;
  float inv  = 1.0f / (sqrtf(fmaxf(var, 0.0f)) + EPS_LN);
  if (i >= NPIX) return;
  float* yb = y + (size_t)b * CH * NPIX + i;
  #pragma unroll 4
  for (int c = w * 128; c < w * 128 + 128; ++c) {
    float v = xb[(size_t)c * NPIX];
    yb[(size_t)c * NPIX] = (v - mean) * inv * g[c] + bt[c];
  }
}

// ---------------------------------------------------------------------------
// First depthwise conv (25x25): three convs in one pass, f32 out. (unchanged)
// ---------------------------------------------------------------------------
__global__ void dwconv3_kernel(const float* __restrict__ src,
    const float* __restrict__ w0, const float* __restrict__ b0,
    const float* __restrict__ w1, const float* __restrict__ b1,
    const float* __restrict__ w2, const float* __restrict__ b2,
    float* __restrict__ d0, float* __restrict__ d1, float* __restrict__ d2,
    int Hc, int Wc) {
  size_t idx = (size_t)blockIdx.x * blockDim.x + threadIdx.x;
  size_t total = (size_t)BATCH * CH * Hc * Wc;
  if (idx >= total) return;
  int wp = (int)(idx % Wc);
  int hp = (int)((idx / Wc) % Hc);
  int c  = (int)((idx / ((size_t)Wc * Hc)) % CH);
  const float* f0 = w0 + c * 9;
  const float* f1 = w1 + c * 9;
  const float* f2 = w2 + c * 9;
  float a0 = 0.f, a1 = 0.f, a2 = 0.f;
  #pragma unroll
  for (int kh = -1; kh <= 1; ++kh) {
    int h2 = hp + kh; if (h2 < 0 || h2 >= Hc) continue;
    #pragma unroll
    for (int kw = -1; kw <= 1; ++kw) {
      int w2p = wp + kw; if (w2p < 0 || w2p >= Wc) continue;
      float v = src[idx + (size_t)kh * Wc + kw];
      int wi = (kh + 1) * 3 + (kw + 1);
      a0 += v * f0[wi]; a1 += v * f1[wi]; a2 += v * f2[wi];
    }
  }
  d0[idx] = a0 + b0[c];
  d1[idx] = a1 + b1[c];
  d2[idx] = a2 + b2[c];
}

// ---------------------------------------------------------------------------
// spe depthwise conv (5x125): q,k -> bf16 [c][640] padded; v -> f32. (unchanged)
// ---------------------------------------------------------------------------
__global__ void dwconv_spe_kernel(const float* __restrict__ src,
    const float* __restrict__ w0, const float* __restrict__ b0,
    const float* __restrict__ w1, const float* __restrict__ b1,
    const float* __restrict__ w2, const float* __restrict__ b2,
    __bf16* __restrict__ q16, __bf16* __restrict__ k16, float* __restrict__ v) {
  size_t idx = (size_t)blockIdx.x * blockDim.x + threadIdx.x;
  if (idx >= (size_t)BATCH * CH * 640) return;
  int n = (int)(idx % 640);
  int c = (int)((idx / 640) % CH);
  int b = (int)(idx / ((size_t)640 * CH));
  if (n >= NPIX) { q16[idx] = (__bf16)0.f; k16[idx] = (__bf16)0.f; return; }
  int hp = n / 125, wp = n % 125;
  size_t base = ((size_t)b * CH + c) * NPIX;
  const float* f0 = w0 + c * 9;
  const float* f1 = w1 + c * 9;
  const float* f2 = w2 + c * 9;
  float a0 = 0.f, a1 = 0.f, a2 = 0.f;
  #pragma unroll
  for (int kh = -1; kh <= 1; ++kh) {
    int h2 = hp + kh; if (h2 < 0 || h2 >= 5) continue;
    #pragma unroll
    for (int kw = -1; kw <= 1; ++kw) {
      int w2p = wp + kw; if (w2p < 0 || w2p >= 125) continue;
      float vv = src[base + h2 * 125 + w2p];
      int wi = (kh + 1) * 3 + (kw + 1);
      a0 += vv * f0[wi]; a1 += vv * f1[wi]; a2 += vv * f2[wi];
    }
  }
  q16[idx] = (__bf16)(a0 + b0[c]);
  k16[idx] = (__bf16)(a1 + b1[c]);
  v[base + n] = a2 + b2[c];
}

// ---------------------------------------------------------------------------
// Transpose+cast q,k: [b][h*64+d][n] f32 -> [bh][n][64] bf16. (unchanged)
// ---------------------------------------------------------------------------
__global__ __launch_bounds__(256) void qk_to_bf16T(
    const float* __restrict__ q, const float* __restrict__ k,
    __bf16* __restrict__ qT, __bf16* __restrict__ kT) {
  __shared__ __bf16 tq[64][65];
  __shared__ __bf16 tk[64][65];
  int bh = blockIdx.y;
  int n0 = blockIdx.x * 64;
  int b = bh >> 3, h = bh & 7;
  const float* qb = q + (size_t)(b * CH + h * HDIM) * NPIX;
  const float* kb = k + (size_t)(b * CH + h * HDIM) * NPIX;
  #pragma unroll
  for (int it = 0; it < 16; ++it) {
    int idx = threadIdx.x + it * 256;
    int d = idx >> 6, n = idx & 63;
    int nn = n0 + n;
    float qv = (nn < NPIX) ? qb[(size_t)d * NPIX + nn] : 0.f;
    float kv = (nn < NPIX) ? kb[(size_t)d * NPIX + nn] : 0.f;
    tq[n][d] = (__bf16)qv;
    tk[n][d] = (__bf16)kv;
  }
  __syncthreads();
  size_t obase = (size_t)bh * NPIX;
  #pragma unroll
  for (int it = 0; it < 16; ++it) {
    int idx = threadIdx.x + it * 256;
    int n = idx >> 6, d = idx & 63;
    int nn = n0 + n;
    if (nn < NPIX) {
      qT[(obase + nn) * 64 + d] = tq[n][d];
      kT[(obase + nn) * 64 + d] = tk[n][d];
    }
  }
}

// v: [c][625] f32 -> [c][640] bf16. (unchanged)
__global__ void v_to_bf16(const float* __restrict__ v, __bf16* __restrict__ v16) {
  int row = blockIdx.x;
  const float* src = v + (size_t)row * NPIX;
  __bf16* dst = v16 + (size_t)row * 640;
  for (int n = threadIdx.x; n < NPIX; n += 256) dst[n] = (__bf16)src[n];
}

// ---------------------------------------------------------------------------
// MFMA head attention v3: cooperative 4-wave split.
// Block = 256 thr = 4 waves, one (b, h, 16-q-row tile).
// Phase 1: wave w computes S for keys [160w,160w+160) -> s[10] frags/lane
//          (only 40 VGPR of S state -> all 20 global K-loads pipeline).
// Softmax: per-wave partials, cross-wave combine via tiny LDS buffer.
// P -> shared LDS [16][648] bf16 (stride 1296B: b128 reads hit bank floor).
// Phase 2: wave w computes d-slice [16w,16w+16): 20 LDS P-frags + 20 global
//          V-loads + 20 MFMAs. Output staged via LDS for coalesced stores.
// ---------------------------------------------------------------------------
__global__ __launch_bounds__(256) void head_attn_mfma3(
    const __bf16* __restrict__ qT, const __bf16* __restrict__ kT,
    const __bf16* __restrict__ vB, float* __restrict__ out) {
  __shared__ __align__(16) union SmU {
    unsigned char p[16 * 1296];   // P: 16 rows x 648 cols bf16 (640 used)
    float ostage[64][17];         // output transpose staging (reused)
  } sm;
  __shared__ float red_max[4][16];
  __shared__ float red_sum[4][16];

  int t = threadIdx.x;
  int w = t >> 6, lane = t & 63, g = lane >> 4, li = lane & 15;
  int h = blockIdx.y, b = blockIdx.z;
  int bh = b * HEADS + h;
  int i0 = blockIdx.x * 16;
  const __bf16* Qb = qT + (size_t)bh * NPIX * 64;
  const __bf16* Kb = kT + (size_t)bh * NPIX * 64;

  // Q A-frags (same for all 4 waves): lane holds Q[i0+li][8g+j (+32)]
  bf16x8 aq0, aq1;
  {
    int qr = i0 + li; if (qr > NPIX - 1) qr = NPIX - 1;
    const __bf16* qp = Qb + (size_t)qr * 64 + 8 * g;
    aq0 = *(const bf16x8*)(qp);
    aq1 = *(const bf16x8*)(qp + 32);
  }

  // ---- phase 1: S frags for this wave's 160 keys ----
  f32x4 s[10];
  #pragma unroll
  for (int cfl = 0; cfl < 10; ++cfl) {
    int kc = (w * 10 + cfl) * 16 + li;
    int kcl = kc > NPIX - 1 ? NPIX - 1 : kc;
    const __bf16* kp = Kb + (size_t)kcl * 64 + 8 * g;
    bf16x8 bk0 = *(const bf16x8*)(kp);
    bf16x8 bk1 = *(const bf16x8*)(kp + 32);
    f32x4 a = (f32x4){0.f, 0.f, 0.f, 0.f};
    a = __builtin_amdgcn_mfma_f32_16x16x32_bf16(aq0, bk0, a, 0, 0, 0);
    a = __builtin_amdgcn_mfma_f32_16x16x32_bf16(aq1, bk1, a, 0, 0, 0);
    s[cfl] = a * SCALE;
  }
  // mask invalid keys (global cf=39 covers 624+li; only li==0 valid)
  if (w == 3 && li > 0) {
    s[9][0] = -1e30f; s[9][1] = -1e30f; s[9][2] = -1e30f; s[9][3] = -1e30f;
  }

  // ---- per-wave partial max ----
  #pragma unroll
  for (int r = 0; r < 4; ++r) {
    float mx = s[0][r];
    #pragma unroll
    for (int cfl = 1; cfl < 10; ++cfl) mx = fmaxf(mx, s[cfl][r]);
    mx = fmaxf(mx, __shfl_xor(mx, 1));
    mx = fmaxf(mx, __shfl_xor(mx, 2));
    mx = fmaxf(mx, __shfl_xor(mx, 4));
    mx = fmaxf(mx, __shfl_xor(mx, 8));
    if (li == 0) red_max[w][4 * g + r] = mx;
  }
  __syncthreads();

  // ---- combined max, exp, partial sums ----
  #pragma unroll
  for (int r = 0; r < 4; ++r) {
    int row = 4 * g + r;
    float mx = fmaxf(fmaxf(red_max[0][row], red_max[1][row]),
                     fmaxf(red_max[2][row], red_max[3][row]));
    float sum = 0.f;
    #pragma unroll
    for (int cfl = 0; cfl < 10; ++cfl) {
      float p = __expf(s[cfl][r] - mx);
      s[cfl][r] = p;
      sum += p;
    }
    sum += __shfl_xor(sum, 1);
    sum += __shfl_xor(sum, 2);
    sum += __shfl_xor(sum, 4);
    sum += __shfl_xor(sum, 8);
    if (li == 0) red_sum[w][row] = sum;
  }
  __syncthreads();

  // ---- normalize and write P to shared LDS ----
  #pragma unroll
  for (int r = 0; r < 4; ++r) {
    int row = 4 * g + r;
    float l = red_sum[0][row] + red_sum[1][row] + red_sum[2][row] + red_sum[3][row];
    float inv = 1.0f / l;
    #pragma unroll
    for (int cfl = 0; cfl < 10; ++cfl) {
      int col = (w * 10 + cfl) * 16 + li;
      *(__bf16*)(&sm.p[row * 1296 + col * 2]) = (__bf16)(s[cfl][r] * inv);
    }
  }
  __syncthreads();

  // ---- phase 2: O slice = P @ V for d in [16w, 16w+16) ----
  const __bf16* vrow = vB + (size_t)(b * CH + h * HDIM + w * 16 + li) * 640;
  f32x4 o = (f32x4){0.f, 0.f, 0.f, 0.f};
  #pragma unroll
  for (int ks = 0; ks < 20; ++ks) {
    bf16x8 pa = *(const bf16x8*)(&sm.p[li * 1296 + ks * 64 + 16 * g]);
    bf16x8 bv = *(const bf16x8*)(vrow + ks * 32 + 8 * g);
    o = __builtin_amdgcn_mfma_f32_16x16x32_bf16(pa, bv, o, 0, 0, 0);
  }
  __syncthreads();   // P region about to be reused

  // ---- epilogue: stage O^T, coalesced store ----
  #pragma unroll
  for (int r = 0; r < 4; ++r)
    sm.ostage[w * 16 + li][4 * g + r] = o[r];
  __syncthreads();
  size_t cbase = (size_t)(b * CH + h * HDIM);
  #pragma unroll
  for (int it = 0; it < 4; ++it) {
    int e = t + it * 256;          // 0..1023 over 64 d x 16 n
    int d = e >> 4, nl = e & 15;
    int n = i0 + nl;
    if (n < NPIX) out[(cbase + d) * NPIX + n] = sm.ostage[d][nl];
  }
}

// ---------------------------------------------------------------------------
// MFMA channel attention (unchanged, verified round 2).
// ---------------------------------------------------------------------------
__global__ __launch_bounds__(64) void chan_attn_mfma(
    const __bf16* __restrict__ sq, const __bf16* __restrict__ sk,
    __bf16* __restrict__ Am) {
  int lane = threadIdx.x & 63;
  int g = lane >> 4, li = lane & 15;
  int b = blockIdx.y;
  int cq0 = blockIdx.x * 16;
  const __bf16* qrow  = sq + ((size_t)b * CH + cq0 + li) * 640 + 8 * g;
  const __bf16* kbase = sk + ((size_t)b * CH + li) * 640 + 8 * g;
  f32x4 acc[32];
  #pragma unroll
  for (int i = 0; i < 32; ++i) acc[i] = (f32x4){0.f, 0.f, 0.f, 0.f};
  for (int ks = 0; ks < 20; ++ks) {
    bf16x8 af = *(const bf16x8*)(qrow + ks * 32);
    #pragma unroll
    for (int cf = 0; cf < 32; ++cf) {
      bf16x8 bfr = *(const bf16x8*)(kbase + (size_t)cf * 16 * 640 + ks * 32);
      acc[cf] = __builtin_amdgcn_mfma_f32_16x16x32_bf16(af, bfr, acc[cf], 0, 0, 0);
    }
  }
  #pragma unroll
  for (int i = 0; i < 32; ++i) acc[i] = acc[i] * SCALE;
  __bf16* Ab = Am + ((size_t)b * CH + cq0) * CH;
  #pragma unroll
  for (int r = 0; r < 4; ++r) {
    float mx = -1e30f;
    #pragma unroll
    for (int cf = 0; cf < 32; ++cf) mx = fmaxf(mx, acc[cf][r]);
    mx = fmaxf(mx, __shfl_xor(mx, 1));
    mx = fmaxf(mx, __shfl_xor(mx, 2));
    mx = fmaxf(mx, __shfl_xor(mx, 4));
    mx = fmaxf(mx, __shfl_xor(mx, 8));
    float sum = 0.f;
    #pragma unroll
    for (int cf = 0; cf < 32; ++cf) {
      float p = __expf(acc[cf][r] - mx);
      acc[cf][r] = p;
      sum += p;
    }
    sum += __shfl_xor(sum, 1);
    sum += __shfl_xor(sum, 2);
    sum += __shfl_xor(sum, 4);
    sum += __shfl_xor(sum, 8);
    float inv = 1.0f / sum;
    #pragma unroll
    for (int cf = 0; cf < 32; ++cf)
      Ab[(size_t)(4 * g + r) * CH + cf * 16 + li] = (__bf16)(acc[cf][r] * inv);
  }
}

// ---------------------------------------------------------------------------
// NT bf16 MFMA GEMM (unchanged, verified round 2).
// ---------------------------------------------------------------------------
template <int EPI>
__global__ __launch_bounds__(256) void gemm_nt(
    const __bf16* __restrict__ A, long long aBatch,
    const __bf16* __restrict__ B, long long bBatch,
    void* __restrict__ Cout, long long cBatch,
    int M, int N, int K,
    const float* __restrict__ p0, const float* __restrict__ p1,
    const float* __restrict__ res, long long resBatch) {
  __shared__ __align__(16) union {
    struct { unsigned char As[128 * 128]; unsigned char Bs[64 * 128]; } s;
    float Ce[4][64][17];
  } u;
  int t = threadIdx.x;
  int w = t >> 6, lane = t & 63, g = lane >> 4, li = lane & 15;
  int wm = w & 1, wn = w >> 1;
  int n0 = blockIdx.x * 64, m0 = blockIdx.y * 128, b = blockIdx.z;
  const __bf16* Ab = A + (size_t)b * aBatch;
  const __bf16* Bb = B + (size_t)b * bBatch;
  f32x4 acc[4][2];
  #pragma unroll
  for (int i = 0; i < 4; ++i)
    #pragma unroll
    for (int j = 0; j < 2; ++j) acc[i][j] = (f32x4){0.f, 0.f, 0.f, 0.f};

  for (int k0 = 0; k0 < K; k0 += 64) {
    bf16x8 ra[4], rb[2];
    #pragma unroll
    for (int i = 0; i < 4; ++i) {
      int e = t + i * 256;
      int row = e >> 3, cc = e & 7;
      int ar = m0 + row; ar = ar < M ? ar : M - 1;
      ra[i] = *(const bf16x8*)(Ab + (size_t)ar * K + k0 + cc * 8);
    }
    #pragma unroll
    for (int i = 0; i < 2; ++i) {
      int e = t + i * 256;
      int row = e >> 3, cc = e & 7;
      rb[i] = *(const bf16x8*)(Bb + (size_t)(n0 + row) * K + k0 + cc * 8);
    }
    __syncthreads();
    #pragma unroll
    for (int i = 0; i < 4; ++i) {
      int e = t + i * 256; int row = e >> 3, cc = e & 7;
      int off = (row * 128 + cc * 16) ^ ((row & 7) << 4);
      *(bf16x8*)(&u.s.As[off]) = ra[i];
    }
    #pragma unroll
    for (int i = 0; i < 2; ++i) {
      int e = t + i * 256; int row = e >> 3, cc = e & 7;
      int off = (row * 128 + cc * 16) ^ ((row & 7) << 4);
      *(bf16x8*)(&u.s.Bs[off]) = rb[i];
    }
    __syncthreads();
    #pragma unroll
    for (int ks = 0; ks < 2; ++ks) {
      bf16x8 af[4], bfr[2];
      #pragma unroll
      for (int mf = 0; mf < 4; ++mf) {
        int row = wm * 64 + mf * 16 + li;
        int off = (row * 128 + ks * 64 + g * 16) ^ ((row & 7) << 4);
        af[mf] = *(const bf16x8*)(&u.s.As[off]);
      }
      #pragma unroll
      for (int nf = 0; nf < 2; ++nf) {
        int row = wn * 32 + nf * 16 + li;
        int off = (row * 128 + ks * 64 + g * 16) ^ ((row & 7) << 4);
        bfr[nf] = *(const bf16x8*)(&u.s.Bs[off]);
      }
      #pragma unroll
      for (int mf = 0; mf < 4; ++mf)
        #pragma unroll
        for (int nf = 0; nf < 2; ++nf)
          acc[mf][nf] = __builtin_amdgcn_mfma_f32_16x16x32_bf16(
              af[mf], bfr[nf], acc[mf][nf], 0, 0, 0);
    }
    __syncthreads();
  }

  #pragma unroll
  for (int p = 0; p < 2; ++p) {
    __syncthreads();
    #pragma unroll
    for (int mf = 0; mf < 4; ++mf) {
      #pragma unroll
      for (int r = 0; r < 4; ++r)
        u.Ce[w][mf * 16 + 4 * g + r][li] = acc[mf][p][r];
    }
    __syncthreads();
    int m = m0 + wm * 64 + lane;
    int colb = n0 + wn * 32 + p * 16;
    if (m < M) {
      float vv[16];
      #pragma unroll
      for (int c = 0; c < 16; ++c) vv[c] = u.Ce[w][lane][c];
      if (EPI == 0) {
        __bf16* Cb = (__bf16*)Cout + (size_t)b * cBatch + (size_t)m * N + colb;
        bf16x8 o0, o1;
        #pragma unroll
        for (int j = 0; j < 8; ++j) { o0[j] = (__bf16)vv[j]; o1[j] = (__bf16)vv[8 + j]; }
        *(bf16x8*)(Cb) = o0;
        *(bf16x8*)(Cb + 8) = o1;
      } else if (EPI == 1) {
        float* Cf = (float*)Cout + (size_t)b * cBatch + (size_t)m * N + colb;
        const float* rp = res + (size_t)b * resBatch + (size_t)m * N + colb;
        #pragma unroll
        for (int c = 0; c < 16; ++c)
          vv[c] = vv[c] * p0[colb + c] + p1[colb + c] + rp[c];
        #pragma unroll
        for (int c4 = 0; c4 < 4; ++c4)
          *(f32x4*)(Cf + c4 * 4) = (f32x4){vv[c4*4], vv[c4*4+1], vv[c4*4+2], vv[c4*4+3]};
      } else if (EPI == 2) {
        __bf16* Cb = (__bf16*)Cout + (size_t)b * cBatch + (size_t)m * N + colb;
        #pragma unroll
        for (int c = 0; c < 16; ++c) {
          float xg = vv[c] + p0[colb + c];
          vv[c] = 0.5f * xg * (1.0f + erff(xg * 0.70710678118654752f));
        }
        bf16x8 o0, o1;
        #pragma unroll
        for (int j = 0; j < 8; ++j) { o0[j] = (__bf16)vv[j]; o1[j] = (__bf16)vv[8 + j]; }
        *(bf16x8*)(Cb) = o0;
        *(bf16x8*)(Cb + 8) = o1;
      } else {
        float* Cf = (float*)Cout + (size_t)b * cBatch + (size_t)m * N + colb;
        const float* rp = res + (size_t)b * resBatch + (size_t)m * N + colb;
        #pragma unroll
        for (int c = 0; c < 16; ++c)
          vv[c] = vv[c] + p0[colb + c] + rp[c];
        #pragma unroll
        for (int c4 = 0; c4 < 4; ++c4)
          *(f32x4*)(Cf + c4 * 4) = (f32x4){vv[c4*4], vv[c4*4+1], vv[c4*4+2], vv[c4*4+3]};
      }
    }
  }
}

// ---------------------------------------------------------------------------
// Batched tiled transpose (unchanged).
// ---------------------------------------------------------------------------
template <typename TO>
__global__ __launch_bounds__(256) void transpose_bat(
    const float* __restrict__ in, TO* __restrict__ out, int R, int Cc) {
  __shared__ float tile[64][65];
  int b = blockIdx.z;
  int c0 = blockIdx.x * 64, r0 = blockIdx.y * 64;
  const float* ib = in + (size_t)b * R * Cc;
  TO* ob = out + (size_t)b * R * Cc;
  for (int e = threadIdx.x; e < 4096; e += 256) {
    int rr = e >> 6, cc = e & 63;
    int r = r0 + rr, c = c0 + cc;
    tile[rr][cc] = (r < R && c < Cc) ? ib[(size_t)r * Cc + c] : 0.f;
  }
  __syncthreads();
  for (int e = threadIdx.x; e < 4096; e += 256) {
    int cc = e >> 6, rr = e & 63;
    int r = r0 + rr, c = c0 + cc;
    if (r < R && c < Cc) ob[(size_t)c * R + r] = (TO)tile[rr][cc];
  }
}

// ---------------------------------------------------------------------------
// Row LayerNorm (unchanged).
// ---------------------------------------------------------------------------
__global__ __launch_bounds__(256) void ln2_row_kernel(
    const float* __restrict__ y, const float* __restrict__ g,
    const float* __restrict__ bt, __bf16* __restrict__ o) {
  int row = blockIdx.x * 4 + (threadIdx.x >> 6);
  int lane = threadIdx.x & 63;
  const float* yr = y + (size_t)row * CH + lane * 8;
  f32x4 v0 = *(const f32x4*)(yr);
  f32x4 v1 = *(const f32x4*)(yr + 4);
  float s = v0[0]+v0[1]+v0[2]+v0[3]+v1[0]+v1[1]+v1[2]+v1[3];
  float ss = v0[0]*v0[0]+v0[1]*v0[1]+v0[2]*v0[2]+v0[3]*v0[3]
           + v1[0]*v1[0]+v1[1]*v1[1]+v1[2]*v1[2]+v1[3]*v1[3];
  #pragma unroll
  for (int off = 32; off > 0; off >>= 1) {
    s  += __shfl_xor(s, off);
    ss += __shfl_xor(ss, off);
  }
  float mean = s * (1.0f / CH);
  float var  = ss * (1.0f / CH) - mean * mean;
  float inv  = 1.0f / (sqrtf(fmaxf(var, 0.0f)) + EPS_LN);
  f32x4 g0 = *(const f32x4*)(g + lane * 8);
  f32x4 g1 = *(const f32x4*)(g + lane * 8 + 4);
  f32x4 b0 = *(const f32x4*)(bt + lane * 8);
  f32x4 b1 = *(const f32x4*)(bt + lane * 8 + 4);
  bf16x8 ov;
  #pragma unroll
  for (int j = 0; j < 4; ++j) ov[j]     = (__bf16)((v0[j] - mean) * inv * g0[j] + b0[j]);
  #pragma unroll
  for (int j = 0; j < 4; ++j) ov[4 + j] = (__bf16)((v1[j] - mean) * inv * g1[j] + b1[j]);
  *(bf16x8*)(o + (size_t)row * CH + lane * 8) = ov;
}

__global__ void cast_bf16_kernel(const float* __restrict__ s, __bf16* __restrict__ d, int n) {
  int i = blockIdx.x * 256 + threadIdx.x;
  if (i < n) d[i] = (__bf16)s[i];
}

__global__ void bn_prep(const float* __restrict__ g, const float* __restrict__ bt,
                        const float* __restrict__ mean, const float* __restrict__ var,
                        float* __restrict__ scale, float* __restrict__ shift) {
  int c = blockIdx.x * blockDim.x + threadIdx.x;
  if (c >= CH) return;
  float s = g[c] * rsqrtf(var[c] + EPS_BN);
  scale[c] = s;
  shift[c] = bt[c] - mean[c] * s;
}

// ---------------------------------------------------------------------------
extern "C" void kernel_launch(void* const* d_in, const int* in_sizes, int n_in,
                              void* d_out, int out_size, void* d_ws, size_t ws_size,
                              hipStream_t stream) {
  const float* x      = (const float*)d_in[0];
  const float* ln1_g  = (const float*)d_in[1];
  const float* ln1_b  = (const float*)d_in[2];
  const float* wq     = (const float*)d_in[3];
  const float* bq     = (const float*)d_in[4];
  const float* wk     = (const float*)d_in[5];
  const float* bk     = (const float*)d_in[6];
  const float* wv     = (const float*)d_in[7];
  const float* bv     = (const float*)d_in[8];
  const float* swq    = (const float*)d_in[9];
  const float* sbq    = (const float*)d_in[10];
  const float* swk    = (const float*)d_in[11];
  const float* sbk    = (const float*)d_in[12];
  const float* swv    = (const float*)d_in[13];
  const float* sbv    = (const float*)d_in[14];
  const float* proj_w = (const float*)d_in[15];
  const float* bn_g   = (const float*)d_in[16];
  const float* bn_b   = (const float*)d_in[17];
  const float* bn_m   = (const float*)d_in[18];
  const float* bn_v   = (const float*)d_in[19];
  const float* ln2_g  = (const float*)d_in[20];
  const float* ln2_b  = (const float*)d_in[21];
  const float* w1     = (const float*)d_in[22];
  const float* b1     = (const float*)d_in[23];
  const float* w2     = (const float*)d_in[24];
  const float* b2     = (const float*)d_in[25];

  char* W = (char*)d_ws;
  const size_t SZB = 20480000;  // bytes per 16*512*625 f32 slot
  char* S0 = W;
  char* S1 = W + SZB;
  char* S2 = W + 2 * SZB;
  char* S3 = W + 3 * SZB;
  char* S4 = W + 4 * SZB;

  float*  xln   = (float*)S0;
  float*  qb    = (float*)S1;
  float*  kb    = (float*)S2;
  float*  vb    = (float*)S3;
  __bf16* qT    = (__bf16*)S0;
  __bf16* kTp   = qT + (size_t)BATCH * HEADS * NPIX * 64;
  __bf16* v16   = (__bf16*)d_out;
  float*  ab    = (float*)S4;
  __bf16* sq16  = (__bf16*)S1;
  __bf16* sk16  = (__bf16*)S2;
  float*  sv    = (float*)S3;
  __bf16* svT   = (__bf16*)S4;
  __bf16* Amat  = (__bf16*)S0;
  __bf16* pw16  = (__bf16*)(S0 + 10485760);
  __bf16* w116  = (__bf16*)(S0 + 10485760 + 524288);
  __bf16* w216  = (__bf16*)(S0 + 10485760 + 524288 + 2097152);
  float*  bnsc  = (float*)(S0 + 10485760 + 524288 + 2097152 + 2097152);
  float*  bnsh  = bnsc + CH;
  __bf16* xoutT = (__bf16*)S1;
  float*  x_nc  = (float*)S4;
  float*  y1_nc = (float*)S3;
  __bf16* y1ln  = (__bf16*)S0;
  __bf16* h1T   = (__bf16*)S1;   // spans S1+S2
  float*  tmp_nc = (float*)S4;

  const size_t SZ = (size_t)BATCH * CH * NPIX;

  // 1. LN1: x -> xln [c][n]
  ln_kernel2<<<dim3(10, BATCH), 256, 0, stream>>>(x, ln1_g, ln1_b, xln);
  // 2. q,k,v depthwise convs (25x25), f32
  dwconv3_kernel<<<(int)((SZ + 255) / 256), 256, 0, stream>>>(
      xln, wq, bq, wk, bk, wv, bv, qb, kb, vb, 25, 25);
  // 3. bf16 conversions for head attention
  qk_to_bf16T<<<dim3(10, BATCH * HEADS), 256, 0, stream>>>(qb, kb, qT, kTp);
  v_to_bf16<<<dim3(BATCH * CH), 256, 0, stream>>>(vb, v16);
  // 4. MFMA head attention v3 (4-wave cooperative) -> ab [c][n] f32
  head_attn_mfma3<<<dim3(40, HEADS, BATCH), 256, 0, stream>>>(qT, kTp, v16, ab);
  // 5. spe convs (5x125): sq16,sk16 bf16 [c][640]; sv f32 [c][625]
  dwconv_spe_kernel<<<(int)(((size_t)BATCH * CH * 640 + 255) / 256), 256, 0, stream>>>(
      ab, swq, sbq, swk, sbk, swv, sbv, sq16, sk16, sv);
  // 6. sv -> svT bf16 [b][625][512]
  transpose_bat<__bf16><<<dim3(10, 8, BATCH), 256, 0, stream>>>(sv, svT, CH, NPIX);
  // 7. weight casts + BN fold
  cast_bf16_kernel<<<1024, 256, 0, stream>>>(proj_w, pw16, CH * CH);
  cast_bf16_kernel<<<4096, 256, 0, stream>>>(w1, w116, HIDD * CH);
  cast_bf16_kernel<<<4096, 256, 0, stream>>>(w2, w216, CH * HIDD);
  bn_prep<<<2, 256, 0, stream>>>(bn_g, bn_b, bn_m, bn_v, bnsc, bnsh);
  // 8. channel attention -> Amat bf16 [b][512][512]
  chan_attn_mfma<<<dim3(32, BATCH), 64, 0, stream>>>(sq16, sk16, Amat);
  // 9. G1: xoutT[b] = svT (625x512) . Amat^T -> bf16 [b][625][512]
  gemm_nt<0><<<dim3(8, 5, BATCH), 256, 0, stream>>>(
      svT, (long long)NPIX * CH, Amat, (long long)CH * CH,
      xoutT, (long long)NPIX * CH, NPIX, CH, CH,
      nullptr, nullptr, nullptr, 0);
  // 10. x -> x_nc f32 [b][625][512]
  transpose_bat<float><<<dim3(10, 8, BATCH), 256, 0, stream>>>(x, x_nc, CH, NPIX);
  // 11. G2: y1_nc = BN(xoutT . pw16^T) + x_nc   (f32, [10000][512])
  gemm_nt<1><<<dim3(8, 79, 1), 256, 0, stream>>>(
      xoutT, 0LL, pw16, 0LL, y1_nc, 0LL, BATCH * NPIX, CH, CH,
      bnsc, bnsh, x_nc, 0LL);
  // 12. LN2 (row-wise) -> y1ln bf16
  ln2_row_kernel<<<BATCH * NPIX / 4, 256, 0, stream>>>(y1_nc, ln2_g, ln2_b, y1ln);
  // 13. G3: h1T = gelu(y1ln . w116^T + b1)  bf16 [10000][2048]
  gemm_nt<2><<<dim3(32, 79, 1), 256, 0, stream>>>(
      y1ln, 0LL, w116, 0LL, h1T, 0LL, BATCH * NPIX, HIDD, CH,
      b1, nullptr, nullptr, 0LL);
  // 14. G4: tmp_nc = h1T . w216^T + b2 + y1_nc  (f32 [10000][512])
  gemm_nt<3><<<dim3(8, 79, 1), 256, 0, stream>>>(
      h1T, 0LL, w216, 0LL, tmp_nc, 0LL, BATCH * NPIX, CH, HIDD,
      b2, nullptr, y1_nc, 0LL);
  // 15. tmp_nc [b][625][512] -> d_out [b][512][625]
  transpose_bat<float><<<dim3(8, 10, BATCH), 256, 0, stream>>>(
      tmp_nc, (float*)d_out, NPIX, CH);
}

// Round 7
// 582.597 us; speedup vs baseline: 5.4494x; 1.0171x over previous
//
#include <hip/hip_runtime.h>
#include <math.h>

// Shapes
constexpr int BATCH = 16;
constexpr int CH    = 512;
constexpr int NPIX  = 625;   // 25*25 == 5*125
constexpr int HEADS = 8;
constexpr int HDIM  = 64;
constexpr int HIDD  = 2048;

constexpr float EPS_LN = 1e-5f;
constexpr float EPS_BN = 1e-5f;
constexpr float SCALE  = 0.125f;   // hd^-0.5, both attentions

typedef __bf16 bf16x8 __attribute__((ext_vector_type(8)));
typedef float  f32x4  __attribute__((ext_vector_type(4)));

static __device__ inline unsigned pack_bf16(float lo, float hi) {
  union { __bf16 h; unsigned short u; } a, b;
  a.h = (__bf16)lo; b.h = (__bf16)hi;
  return ((unsigned)b.u << 16) | (unsigned)a.u;
}

// ---------------------------------------------------------------------------
// Channel LayerNorm v2 (unchanged).
// ---------------------------------------------------------------------------
__global__ __launch_bounds__(256) void ln_kernel2(
    const float* __restrict__ x, const float* __restrict__ g,
    const float* __restrict__ bt, float* __restrict__ y) {
  __shared__ float ps[4][64];
  __shared__ float pss[4][64];
  int lane = threadIdx.x & 63;
  int w    = threadIdx.x >> 6;
  int b    = blockIdx.y;
  int i    = blockIdx.x * 64 + lane;
  int ic   = i < NPIX ? i : NPIX - 1;
  const float* xb = x + (size_t)b * CH * NPIX + ic;
  float s = 0.f, ss = 0.f;
  #pragma unroll 4
  for (int c = w * 128; c < w * 128 + 128; ++c) {
    float v = xb[(size_t)c * NPIX];
    s += v; ss += v * v;
  }
  ps[w][lane] = s; pss[w][lane] = ss;
  __syncthreads();
  float st  = ps[0][lane] + ps[1][lane] + ps[2][lane] + ps[3][lane];
  float sst = pss[0][lane] + pss[1][lane] + pss[2][lane] + pss[3][lane];
  float mean = st * (1.0f / CH);
  float var  = sst * (1.0f / CH) - mean * mean;
  float inv  = 1.0f / (sqrtf(fmaxf(var, 0.0f)) + EPS_LN);
  if (i >= NPIX) return;
  float* yb = y + (size_t)b * CH * NPIX + i;
  #pragma unroll 4
  for (int c = w * 128; c < w * 128 + 128; ++c) {
    float v = xb[(size_t)c * NPIX];
    yb[(size_t)c * NPIX] = (v - mean) * inv * g[c] + bt[c];
  }
}

// ---------------------------------------------------------------------------
// First depthwise conv (25x25): three convs in one pass, f32 out. (unchanged)
// ---------------------------------------------------------------------------
__global__ void dwconv3_kernel(const float* __restrict__ src,
    const float* __restrict__ w0, const float* __restrict__ b0,
    const float* __restrict__ w1, const float* __restrict__ b1,
    const float* __restrict__ w2, const float* __restrict__ b2,
    float* __restrict__ d0, float* __restrict__ d1, float* __restrict__ d2,
    int Hc, int Wc) {
  size_t idx = (size_t)blockIdx.x * blockDim.x + threadIdx.x;
  size_t total = (size_t)BATCH * CH * Hc * Wc;
  if (idx >= total) return;
  int wp = (int)(idx % Wc);
  int hp = (int)((idx / Wc) % Hc);
  int c  = (int)((idx / ((size_t)Wc * Hc)) % CH);
  const float* f0 = w0 + c * 9;
  const float* f1 = w1 + c * 9;
  const float* f2 = w2 + c * 9;
  float a0 = 0.f, a1 = 0.f, a2 = 0.f;
  #pragma unroll
  for (int kh = -1; kh <= 1; ++kh) {
    int h2 = hp + kh; if (h2 < 0 || h2 >= Hc) continue;
    #pragma unroll
    for (int kw = -1; kw <= 1; ++kw) {
      int w2p = wp + kw; if (w2p < 0 || w2p >= Wc) continue;
      float v = src[idx + (size_t)kh * Wc + kw];
      int wi = (kh + 1) * 3 + (kw + 1);
      a0 += v * f0[wi]; a1 += v * f1[wi]; a2 += v * f2[wi];
    }
  }
  d0[idx] = a0 + b0[c];
  d1[idx] = a1 + b1[c];
  d2[idx] = a2 + b2[c];
}

// ---------------------------------------------------------------------------
// spe depthwise conv (5x125): q,k -> bf16 [c][640] padded; v -> f32. (unchanged)
// ---------------------------------------------------------------------------
__global__ void dwconv_spe_kernel(const float* __restrict__ src,
    const float* __restrict__ w0, const float* __restrict__ b0,
    const float* __restrict__ w1, const float* __restrict__ b1,
    const float* __restrict__ w2, const float* __restrict__ b2,
    __bf16* __restrict__ q16, __bf16* __restrict__ k16, float* __restrict__ v) {
  size_t idx = (size_t)blockIdx.x * blockDim.x + threadIdx.x;
  if (idx >= (size_t)BATCH * CH * 640) return;
  int n = (int)(idx % 640);
  int c = (int)((idx / 640) % CH);
  int b = (int)(idx / ((size_t)640 * CH));
  if (n >= NPIX) { q16[idx] = (__bf16)0.f; k16[idx] = (__bf16)0.f; return; }
  int hp = n / 125, wp = n % 125;
  size_t base = ((size_t)b * CH + c) * NPIX;
  const float* f0 = w0 + c * 9;
  const float* f1 = w1 + c * 9;
  const float* f2 = w2 + c * 9;
  float a0 = 0.f, a1 = 0.f, a2 = 0.f;
  #pragma unroll
  for (int kh = -1; kh <= 1; ++kh) {
    int h2 = hp + kh; if (h2 < 0 || h2 >= 5) continue;
    #pragma unroll
    for (int kw = -1; kw <= 1; ++kw) {
      int w2p = wp + kw; if (w2p < 0 || w2p >= 125) continue;
      float vv = src[base + h2 * 125 + w2p];
      int wi = (kh + 1) * 3 + (kw + 1);
      a0 += vv * f0[wi]; a1 += vv * f1[wi]; a2 += vv * f2[wi];
    }
  }
  q16[idx] = (__bf16)(a0 + b0[c]);
  k16[idx] = (__bf16)(a1 + b1[c]);
  v[base + n] = a2 + b2[c];
}

// ---------------------------------------------------------------------------
// Transpose+cast q,k: [b][h*64+d][n] f32 -> [bh][n][64] bf16. (unchanged)
// ---------------------------------------------------------------------------
__global__ __launch_bounds__(256) void qk_to_bf16T(
    const float* __restrict__ q, const float* __restrict__ k,
    __bf16* __restrict__ qT, __bf16* __restrict__ kT) {
  __shared__ __bf16 tq[64][65];
  __shared__ __bf16 tk[64][65];
  int bh = blockIdx.y;
  int n0 = blockIdx.x * 64;
  int b = bh >> 3, h = bh & 7;
  const float* qb = q + (size_t)(b * CH + h * HDIM) * NPIX;
  const float* kb = k + (size_t)(b * CH + h * HDIM) * NPIX;
  #pragma unroll
  for (int it = 0; it < 16; ++it) {
    int idx = threadIdx.x + it * 256;
    int d = idx >> 6, n = idx & 63;
    int nn = n0 + n;
    float qv = (nn < NPIX) ? qb[(size_t)d * NPIX + nn] : 0.f;
    float kv = (nn < NPIX) ? kb[(size_t)d * NPIX + nn] : 0.f;
    tq[n][d] = (__bf16)qv;
    tk[n][d] = (__bf16)kv;
  }
  __syncthreads();
  size_t obase = (size_t)bh * NPIX;
  #pragma unroll
  for (int it = 0; it < 16; ++it) {
    int idx = threadIdx.x + it * 256;
    int n = idx >> 6, d = idx & 63;
    int nn = n0 + n;
    if (nn < NPIX) {
      qT[(obase + nn) * 64 + d] = tq[n][d];
      kT[(obase + nn) * 64 + d] = tk[n][d];
    }
  }
}

// v: [c][625] f32 -> [c][640] bf16. (unchanged)
__global__ void v_to_bf16(const float* __restrict__ v, __bf16* __restrict__ v16) {
  int row = blockIdx.x;
  const float* src = v + (size_t)row * NPIX;
  __bf16* dst = v16 + (size_t)row * 640;
  for (int n = threadIdx.x; n < NPIX; n += 256) dst[n] = (__bf16)src[n];
}

// ---------------------------------------------------------------------------
// MFMA head attention v4: 4-wave cooperative + conflict-free packed P-writes.
// vs v3: (a) P written via pack_bf16+shfl pairing -> 20 b32 writes/thread,
//        2-way bank spread (free); (b) P left unnormalized, 1/l folded into
//        output; (c) PV split into 2 accumulators for MFMA ILP.
// ---------------------------------------------------------------------------
__global__ __launch_bounds__(256) void head_attn_mfma4(
    const __bf16* __restrict__ qT, const __bf16* __restrict__ kT,
    const __bf16* __restrict__ vB, float* __restrict__ out) {
  __shared__ __align__(16) union SmU {
    unsigned char p[16 * 1296];   // P: 16 rows x 648 cols bf16 (640 used)
    float ostage[64][17];         // output transpose staging (reused)
  } sm;
  __shared__ float red_max[4][16];
  __shared__ float red_sum[4][16];

  int t = threadIdx.x;
  int w = t >> 6, lane = t & 63, g = lane >> 4, li = lane & 15;
  int h = blockIdx.y, b = blockIdx.z;
  int bh = b * HEADS + h;
  int i0 = blockIdx.x * 16;
  const __bf16* Qb = qT + (size_t)bh * NPIX * 64;
  const __bf16* Kb = kT + (size_t)bh * NPIX * 64;

  // Q A-frags: lane holds Q[i0+li][8g+j (+32)]
  bf16x8 aq0, aq1;
  {
    int qr = i0 + li; if (qr > NPIX - 1) qr = NPIX - 1;
    const __bf16* qp = Qb + (size_t)qr * 64 + 8 * g;
    aq0 = *(const bf16x8*)(qp);
    aq1 = *(const bf16x8*)(qp + 32);
  }

  // ---- phase 1: S frags for this wave's 160 keys ----
  f32x4 s[10];
  #pragma unroll
  for (int cfl = 0; cfl < 10; ++cfl) {
    int kc = (w * 10 + cfl) * 16 + li;
    int kcl = kc > NPIX - 1 ? NPIX - 1 : kc;
    const __bf16* kp = Kb + (size_t)kcl * 64 + 8 * g;
    bf16x8 bk0 = *(const bf16x8*)(kp);
    bf16x8 bk1 = *(const bf16x8*)(kp + 32);
    f32x4 a = (f32x4){0.f, 0.f, 0.f, 0.f};
    a = __builtin_amdgcn_mfma_f32_16x16x32_bf16(aq0, bk0, a, 0, 0, 0);
    a = __builtin_amdgcn_mfma_f32_16x16x32_bf16(aq1, bk1, a, 0, 0, 0);
    s[cfl] = a * SCALE;
  }
  // mask invalid keys (global cf=39 covers 624+li; only li==0 valid)
  if (w == 3 && li > 0) {
    s[9][0] = -1e30f; s[9][1] = -1e30f; s[9][2] = -1e30f; s[9][3] = -1e30f;
  }

  // ---- per-wave partial max ----
  #pragma unroll
  for (int r = 0; r < 4; ++r) {
    float mx = s[0][r];
    #pragma unroll
    for (int cfl = 1; cfl < 10; ++cfl) mx = fmaxf(mx, s[cfl][r]);
    mx = fmaxf(mx, __shfl_xor(mx, 1));
    mx = fmaxf(mx, __shfl_xor(mx, 2));
    mx = fmaxf(mx, __shfl_xor(mx, 4));
    mx = fmaxf(mx, __shfl_xor(mx, 8));
    if (li == 0) red_max[w][4 * g + r] = mx;
  }
  __syncthreads();

  // ---- combined max, exp, partial sums (P left unnormalized) ----
  #pragma unroll
  for (int r = 0; r < 4; ++r) {
    int row = 4 * g + r;
    float mx = fmaxf(fmaxf(red_max[0][row], red_max[1][row]),
                     fmaxf(red_max[2][row], red_max[3][row]));
    float sum = 0.f;
    #pragma unroll
    for (int cfl = 0; cfl < 10; ++cfl) {
      float p = __expf(s[cfl][r] - mx);
      s[cfl][r] = p;
      sum += p;
    }
    sum += __shfl_xor(sum, 1);
    sum += __shfl_xor(sum, 2);
    sum += __shfl_xor(sum, 4);
    sum += __shfl_xor(sum, 8);
    if (li == 0) red_sum[w][row] = sum;
  }
  __syncthreads();

  // ---- P -> LDS: paired-column packed b32 writes (2-way banks = free) ----
  #pragma unroll
  for (int cfp = 0; cfp < 5; ++cfp) {
    int cf0 = 2 * cfp, cf1 = cf0 + 1;
    #pragma unroll
    for (int r = 0; r < 4; ++r) {
      float v0 = s[cf0][r], v1 = s[cf1][r];
      float t0 = __shfl_xor(v0, 1);
      float t1 = __shfl_xor(v1, 1);
      bool even = (li & 1) == 0;
      float lo = even ? v0 : t1;
      float hi = even ? t0 : v1;
      int col = even ? ((w * 10 + cf0) * 16 + li)
                     : ((w * 10 + cf1) * 16 + li - 1);
      int row = 4 * g + r;
      *(unsigned*)(&sm.p[row * 1296 + col * 2]) = pack_bf16(lo, hi);
    }
  }
  __syncthreads();

  // ---- phase 2: O slice = P @ V for d in [16w, 16w+16), dual accumulators --
  const __bf16* vrow = vB + (size_t)(b * CH + h * HDIM + w * 16 + li) * 640;
  f32x4 oa = (f32x4){0.f, 0.f, 0.f, 0.f};
  f32x4 ob = (f32x4){0.f, 0.f, 0.f, 0.f};
  #pragma unroll
  for (int ks = 0; ks < 20; ks += 2) {
    bf16x8 pa0 = *(const bf16x8*)(&sm.p[li * 1296 + ks * 64 + 16 * g]);
    bf16x8 bv0 = *(const bf16x8*)(vrow + ks * 32 + 8 * g);
    oa = __builtin_amdgcn_mfma_f32_16x16x32_bf16(pa0, bv0, oa, 0, 0, 0);
    bf16x8 pa1 = *(const bf16x8*)(&sm.p[li * 1296 + (ks + 1) * 64 + 16 * g]);
    bf16x8 bv1 = *(const bf16x8*)(vrow + (ks + 1) * 32 + 8 * g);
    ob = __builtin_amdgcn_mfma_f32_16x16x32_bf16(pa1, bv1, ob, 0, 0, 0);
  }
  f32x4 o = oa + ob;
  // fold softmax normalization into output (row = q-row 4g+r)
  #pragma unroll
  for (int r = 0; r < 4; ++r) {
    int row = 4 * g + r;
    float l = red_sum[0][row] + red_sum[1][row] + red_sum[2][row] + red_sum[3][row];
    o[r] *= (1.0f / l);
  }
  __syncthreads();   // P region about to be reused

  // ---- epilogue: stage O^T, coalesced store ----
  #pragma unroll
  for (int r = 0; r < 4; ++r)
    sm.ostage[w * 16 + li][4 * g + r] = o[r];
  __syncthreads();
  size_t cbase = (size_t)(b * CH + h * HDIM);
  #pragma unroll
  for (int it = 0; it < 4; ++it) {
    int e = t + it * 256;          // 0..1023 over 64 d x 16 n
    int d = e >> 4, nl = e & 15;
    int n = i0 + nl;
    if (n < NPIX) out[(cbase + d) * NPIX + n] = sm.ostage[d][nl];
  }
}

// ---------------------------------------------------------------------------
// MFMA channel attention v2: 4-wave cooperative split.
// Block = 256 thr, one (b, 16-cq-row tile). Wave w owns ck frags [8w,8w+8)
// (acc state 32 VGPR vs 128). Cross-wave softmax via LDS partials.
// ---------------------------------------------------------------------------
__global__ __launch_bounds__(256) void chan_attn_mfma2(
    const __bf16* __restrict__ sq, const __bf16* __restrict__ sk,
    __bf16* __restrict__ Am) {
  __shared__ float red_max[4][16];
  __shared__ float red_sum[4][16];
  int t = threadIdx.x;
  int w = t >> 6, lane = t & 63, g = lane >> 4, li = lane & 15;
  int b = blockIdx.y;
  int cq0 = blockIdx.x * 16;
  const __bf16* qrow  = sq + ((size_t)b * CH + cq0 + li) * 640 + 8 * g;
  const __bf16* kbase = sk + ((size_t)b * CH + w * 128 + li) * 640 + 8 * g;
  f32x4 acc[8];
  #pragma unroll
  for (int i = 0; i < 8; ++i) acc[i] = (f32x4){0.f, 0.f, 0.f, 0.f};
  for (int ks = 0; ks < 20; ++ks) {
    bf16x8 af = *(const bf16x8*)(qrow + ks * 32);
    #pragma unroll
    for (int cfl = 0; cfl < 8; ++cfl) {
      bf16x8 bfr = *(const bf16x8*)(kbase + (size_t)cfl * 16 * 640 + ks * 32);
      acc[cfl] = __builtin_amdgcn_mfma_f32_16x16x32_bf16(af, bfr, acc[cfl], 0, 0, 0);
    }
  }
  #pragma unroll
  for (int i = 0; i < 8; ++i) acc[i] = acc[i] * SCALE;

  // per-wave partial max
  #pragma unroll
  for (int r = 0; r < 4; ++r) {
    float mx = acc[0][r];
    #pragma unroll
    for (int cfl = 1; cfl < 8; ++cfl) mx = fmaxf(mx, acc[cfl][r]);
    mx = fmaxf(mx, __shfl_xor(mx, 1));
    mx = fmaxf(mx, __shfl_xor(mx, 2));
    mx = fmaxf(mx, __shfl_xor(mx, 4));
    mx = fmaxf(mx, __shfl_xor(mx, 8));
    if (li == 0) red_max[w][4 * g + r] = mx;
  }
  __syncthreads();

  // combined max, exp, partial sums
  #pragma unroll
  for (int r = 0; r < 4; ++r) {
    int row = 4 * g + r;
    float mx = fmaxf(fmaxf(red_max[0][row], red_max[1][row]),
                     fmaxf(red_max[2][row], red_max[3][row]));
    float sum = 0.f;
    #pragma unroll
    for (int cfl = 0; cfl < 8; ++cfl) {
      float p = __expf(acc[cfl][r] - mx);
      acc[cfl][r] = p;
      sum += p;
    }
    sum += __shfl_xor(sum, 1);
    sum += __shfl_xor(sum, 2);
    sum += __shfl_xor(sum, 4);
    sum += __shfl_xor(sum, 8);
    if (li == 0) red_sum[w][row] = sum;
  }
  __syncthreads();

  // normalize + store this wave's 128-col slice
  __bf16* Ab = Am + ((size_t)b * CH + cq0) * CH + w * 128;
  #pragma unroll
  for (int r = 0; r < 4; ++r) {
    int row = 4 * g + r;
    float l = red_sum[0][row] + red_sum[1][row] + red_sum[2][row] + red_sum[3][row];
    float inv = 1.0f / l;
    #pragma unroll
    for (int cfl = 0; cfl < 8; ++cfl)
      Ab[(size_t)row * CH + cfl * 16 + li] = (__bf16)(acc[cfl][r] * inv);
  }
}

// ---------------------------------------------------------------------------
// NT bf16 MFMA GEMM (unchanged, verified round 2).
// ---------------------------------------------------------------------------
template <int EPI>
__global__ __launch_bounds__(256) void gemm_nt(
    const __bf16* __restrict__ A, long long aBatch,
    const __bf16* __restrict__ B, long long bBatch,
    void* __restrict__ Cout, long long cBatch,
    int M, int N, int K,
    const float* __restrict__ p0, const float* __restrict__ p1,
    const float* __restrict__ res, long long resBatch) {
  __shared__ __align__(16) union {
    struct { unsigned char As[128 * 128]; unsigned char Bs[64 * 128]; } s;
    float Ce[4][64][17];
  } u;
  int t = threadIdx.x;
  int w = t >> 6, lane = t & 63, g = lane >> 4, li = lane & 15;
  int wm = w & 1, wn = w >> 1;
  int n0 = blockIdx.x * 64, m0 = blockIdx.y * 128, b = blockIdx.z;
  const __bf16* Ab = A + (size_t)b * aBatch;
  const __bf16* Bb = B + (size_t)b * bBatch;
  f32x4 acc[4][2];
  #pragma unroll
  for (int i = 0; i < 4; ++i)
    #pragma unroll
    for (int j = 0; j < 2; ++j) acc[i][j] = (f32x4){0.f, 0.f, 0.f, 0.f};

  for (int k0 = 0; k0 < K; k0 += 64) {
    bf16x8 ra[4], rb[2];
    #pragma unroll
    for (int i = 0; i < 4; ++i) {
      int e = t + i * 256;
      int row = e >> 3, cc = e & 7;
      int ar = m0 + row; ar = ar < M ? ar : M - 1;
      ra[i] = *(const bf16x8*)(Ab + (size_t)ar * K + k0 + cc * 8);
    }
    #pragma unroll
    for (int i = 0; i < 2; ++i) {
      int e = t + i * 256;
      int row = e >> 3, cc = e & 7;
      rb[i] = *(const bf16x8*)(Bb + (size_t)(n0 + row) * K + k0 + cc * 8);
    }
    __syncthreads();
    #pragma unroll
    for (int i = 0; i < 4; ++i) {
      int e = t + i * 256; int row = e >> 3, cc = e & 7;
      int off = (row * 128 + cc * 16) ^ ((row & 7) << 4);
      *(bf16x8*)(&u.s.As[off]) = ra[i];
    }
    #pragma unroll
    for (int i = 0; i < 2; ++i) {
      int e = t + i * 256; int row = e >> 3, cc = e & 7;
      int off = (row * 128 + cc * 16) ^ ((row & 7) << 4);
      *(bf16x8*)(&u.s.Bs[off]) = rb[i];
    }
    __syncthreads();
    #pragma unroll
    for (int ks = 0; ks < 2; ++ks) {
      bf16x8 af[4], bfr[2];
      #pragma unroll
      for (int mf = 0; mf < 4; ++mf) {
        int row = wm * 64 + mf * 16 + li;
        int off = (row * 128 + ks * 64 + g * 16) ^ ((row & 7) << 4);
        af[mf] = *(const bf16x8*)(&u.s.As[off]);
      }
      #pragma unroll
      for (int nf = 0; nf < 2; ++nf) {
        int row = wn * 32 + nf * 16 + li;
        int off = (row * 128 + ks * 64 + g * 16) ^ ((row & 7) << 4);
        bfr[nf] = *(const bf16x8*)(&u.s.Bs[off]);
      }
      #pragma unroll
      for (int mf = 0; mf < 4; ++mf)
        #pragma unroll
        for (int nf = 0; nf < 2; ++nf)
          acc[mf][nf] = __builtin_amdgcn_mfma_f32_16x16x32_bf16(
              af[mf], bfr[nf], acc[mf][nf], 0, 0, 0);
    }
    __syncthreads();
  }

  #pragma unroll
  for (int p = 0; p < 2; ++p) {
    __syncthreads();
    #pragma unroll
    for (int mf = 0; mf < 4; ++mf) {
      #pragma unroll
      for (int r = 0; r < 4; ++r)
        u.Ce[w][mf * 16 + 4 * g + r][li] = acc[mf][p][r];
    }
    __syncthreads();
    int m = m0 + wm * 64 + lane;
    int colb = n0 + wn * 32 + p * 16;
    if (m < M) {
      float vv[16];
      #pragma unroll
      for (int c = 0; c < 16; ++c) vv[c] = u.Ce[w][lane][c];
      if (EPI == 0) {
        __bf16* Cb = (__bf16*)Cout + (size_t)b * cBatch + (size_t)m * N + colb;
        bf16x8 o0, o1;
        #pragma unroll
        for (int j = 0; j < 8; ++j) { o0[j] = (__bf16)vv[j]; o1[j] = (__bf16)vv[8 + j]; }
        *(bf16x8*)(Cb) = o0;
        *(bf16x8*)(Cb + 8) = o1;
      } else if (EPI == 1) {
        float* Cf = (float*)Cout + (size_t)b * cBatch + (size_t)m * N + colb;
        const float* rp = res + (size_t)b * resBatch + (size_t)m * N + colb;
        #pragma unroll
        for (int c = 0; c < 16; ++c)
          vv[c] = vv[c] * p0[colb + c] + p1[colb + c] + rp[c];
        #pragma unroll
        for (int c4 = 0; c4 < 4; ++c4)
          *(f32x4*)(Cf + c4 * 4) = (f32x4){vv[c4*4], vv[c4*4+1], vv[c4*4+2], vv[c4*4+3]};
      } else if (EPI == 2) {
        __bf16* Cb = (__bf16*)Cout + (size_t)b * cBatch + (size_t)m * N + colb;
        #pragma unroll
        for (int c = 0; c < 16; ++c) {
          float xg = vv[c] + p0[colb + c];
          vv[c] = 0.5f * xg * (1.0f + erff(xg * 0.70710678118654752f));
        }
        bf16x8 o0, o1;
        #pragma unroll
        for (int j = 0; j < 8; ++j) { o0[j] = (__bf16)vv[j]; o1[j] = (__bf16)vv[8 + j]; }
        *(bf16x8*)(Cb) = o0;
        *(bf16x8*)(Cb + 8) = o1;
      } else {
        float* Cf = (float*)Cout + (size_t)b * cBatch + (size_t)m * N + colb;
        const float* rp = res + (size_t)b * resBatch + (size_t)m * N + colb;
        #pragma unroll
        for (int c = 0; c < 16; ++c)
          vv[c] = vv[c] + p0[colb + c] + rp[c];
        #pragma unroll
        for (int c4 = 0; c4 < 4; ++c4)
          *(f32x4*)(Cf + c4 * 4) = (f32x4){vv[c4*4], vv[c4*4+1], vv[c4*4+2], vv[c4*4+3]};
      }
    }
  }
}

// ---------------------------------------------------------------------------
// Batched tiled transpose (unchanged).
// ---------------------------------------------------------------------------
template <typename TO>
__global__ __launch_bounds__(256) void transpose_bat(
    const float* __restrict__ in, TO* __restrict__ out, int R, int Cc) {
  __shared__ float tile[64][65];
  int b = blockIdx.z;
  int c0 = blockIdx.x * 64, r0 = blockIdx.y * 64;
  const float* ib = in + (size_t)b * R * Cc;
  TO* ob = out + (size_t)b * R * Cc;
  for (int e = threadIdx.x; e < 4096; e += 256) {
    int rr = e >> 6, cc = e & 63;
    int r = r0 + rr, c = c0 + cc;
    tile[rr][cc] = (r < R && c < Cc) ? ib[(size_t)r * Cc + c] : 0.f;
  }
  __syncthreads();
  for (int e = threadIdx.x; e < 4096; e += 256) {
    int cc = e >> 6, rr = e & 63;
    int r = r0 + rr, c = c0 + cc;
    if (r < R && c < Cc) ob[(size_t)c * R + r] = (TO)tile[rr][cc];
  }
}

// ---------------------------------------------------------------------------
// Row LayerNorm (unchanged).
// ---------------------------------------------------------------------------
__global__ __launch_bounds__(256) void ln2_row_kernel(
    const float* __restrict__ y, const float* __restrict__ g,
    const float* __restrict__ bt, __bf16* __restrict__ o) {
  int row = blockIdx.x * 4 + (threadIdx.x >> 6);
  int lane = threadIdx.x & 63;
  const float* yr = y + (size_t)row * CH + lane * 8;
  f32x4 v0 = *(const f32x4*)(yr);
  f32x4 v1 = *(const f32x4*)(yr + 4);
  float s = v0[0]+v0[1]+v0[2]+v0[3]+v1[0]+v1[1]+v1[2]+v1[3];
  float ss = v0[0]*v0[0]+v0[1]*v0[1]+v0[2]*v0[2]+v0[3]*v0[3]
           + v1[0]*v1[0]+v1[1]*v1[1]+v1[2]*v1[2]+v1[3]*v1[3];
  #pragma unroll
  for (int off = 32; off > 0; off >>= 1) {
    s  += __shfl_xor(s, off);
    ss += __shfl_xor(ss, off);
  }
  float mean = s * (1.0f / CH);
  float var  = ss * (1.0f / CH) - mean * mean;
  float inv  = 1.0f / (sqrtf(fmaxf(var, 0.0f)) + EPS_LN);
  f32x4 g0 = *(const f32x4*)(g + lane * 8);
  f32x4 g1 = *(const f32x4*)(g + lane * 8 + 4);
  f32x4 b0 = *(const f32x4*)(bt + lane * 8);
  f32x4 b1 = *(const f32x4*)(bt + lane * 8 + 4);
  bf16x8 ov;
  #pragma unroll
  for (int j = 0; j < 4; ++j) ov[j]     = (__bf16)((v0[j] - mean) * inv * g0[j] + b0[j]);
  #pragma unroll
  for (int j = 0; j < 4; ++j) ov[4 + j] = (__bf16)((v1[j] - mean) * inv * g1[j] + b1[j]);
  *(bf16x8*)(o + (size_t)row * CH + lane * 8) = ov;
}

__global__ void cast_bf16_kernel(const float* __restrict__ s, __bf16* __restrict__ d, int n) {
  int i = blockIdx.x * 256 + threadIdx.x;
  if (i < n) d[i] = (__bf16)s[i];
}

__global__ void bn_prep(const float* __restrict__ g, const float* __restrict__ bt,
                        const float* __restrict__ mean, const float* __restrict__ var,
                        float* __restrict__ scale, float* __restrict__ shift) {
  int c = blockIdx.x * blockDim.x + threadIdx.x;
  if (c >= CH) return;
  float s = g[c] * rsqrtf(var[c] + EPS_BN);
  scale[c] = s;
  shift[c] = bt[c] - mean[c] * s;
}

// ---------------------------------------------------------------------------
extern "C" void kernel_launch(void* const* d_in, const int* in_sizes, int n_in,
                              void* d_out, int out_size, void* d_ws, size_t ws_size,
                              hipStream_t stream) {
  const float* x      = (const float*)d_in[0];
  const float* ln1_g  = (const float*)d_in[1];
  const float* ln1_b  = (const float*)d_in[2];
  const float* wq     = (const float*)d_in[3];
  const float* bq     = (const float*)d_in[4];
  const float* wk     = (const float*)d_in[5];
  const float* bk     = (const float*)d_in[6];
  const float* wv     = (const float*)d_in[7];
  const float* bv     = (const float*)d_in[8];
  const float* swq    = (const float*)d_in[9];
  const float* sbq    = (const float*)d_in[10];
  const float* swk    = (const float*)d_in[11];
  const float* sbk    = (const float*)d_in[12];
  const float* swv    = (const float*)d_in[13];
  const float* sbv    = (const float*)d_in[14];
  const float* proj_w = (const float*)d_in[15];
  const float* bn_g   = (const float*)d_in[16];
  const float* bn_b   = (const float*)d_in[17];
  const float* bn_m   = (const float*)d_in[18];
  const float* bn_v   = (const float*)d_in[19];
  const float* ln2_g  = (const float*)d_in[20];
  const float* ln2_b  = (const float*)d_in[21];
  const float* w1     = (const float*)d_in[22];
  const float* b1     = (const float*)d_in[23];
  const float* w2     = (const float*)d_in[24];
  const float* b2     = (const float*)d_in[25];

  char* W = (char*)d_ws;
  const size_t SZB = 20480000;  // bytes per 16*512*625 f32 slot
  char* S0 = W;
  char* S1 = W + SZB;
  char* S2 = W + 2 * SZB;
  char* S3 = W + 3 * SZB;
  char* S4 = W + 4 * SZB;

  float*  xln   = (float*)S0;
  float*  qb    = (float*)S1;
  float*  kb    = (float*)S2;
  float*  vb    = (float*)S3;
  __bf16* qT    = (__bf16*)S0;
  __bf16* kTp   = qT + (size_t)BATCH * HEADS * NPIX * 64;
  __bf16* v16   = (__bf16*)d_out;
  float*  ab    = (float*)S4;
  __bf16* sq16  = (__bf16*)S1;
  __bf16* sk16  = (__bf16*)S2;
  float*  sv    = (float*)S3;
  __bf16* svT   = (__bf16*)S4;
  __bf16* Amat  = (__bf16*)S0;
  __bf16* pw16  = (__bf16*)(S0 + 10485760);
  __bf16* w116  = (__bf16*)(S0 + 10485760 + 524288);
  __bf16* w216  = (__bf16*)(S0 + 10485760 + 524288 + 2097152);
  float*  bnsc  = (float*)(S0 + 10485760 + 524288 + 2097152 + 2097152);
  float*  bnsh  = bnsc + CH;
  __bf16* xoutT = (__bf16*)S1;
  float*  x_nc  = (float*)S4;
  float*  y1_nc = (float*)S3;
  __bf16* y1ln  = (__bf16*)S0;
  __bf16* h1T   = (__bf16*)S1;   // spans S1+S2
  float*  tmp_nc = (float*)S4;

  const size_t SZ = (size_t)BATCH * CH * NPIX;

  // 1. LN1: x -> xln [c][n]
  ln_kernel2<<<dim3(10, BATCH), 256, 0, stream>>>(x, ln1_g, ln1_b, xln);
  // 2. q,k,v depthwise convs (25x25), f32
  dwconv3_kernel<<<(int)((SZ + 255) / 256), 256, 0, stream>>>(
      xln, wq, bq, wk, bk, wv, bv, qb, kb, vb, 25, 25);
  // 3. bf16 conversions for head attention
  qk_to_bf16T<<<dim3(10, BATCH * HEADS), 256, 0, stream>>>(qb, kb, qT, kTp);
  v_to_bf16<<<dim3(BATCH * CH), 256, 0, stream>>>(vb, v16);
  // 4. MFMA head attention v4 -> ab [c][n] f32
  head_attn_mfma4<<<dim3(40, HEADS, BATCH), 256, 0, stream>>>(qT, kTp, v16, ab);
  // 5. spe convs (5x125): sq16,sk16 bf16 [c][640]; sv f32 [c][625]
  dwconv_spe_kernel<<<(int)(((size_t)BATCH * CH * 640 + 255) / 256), 256, 0, stream>>>(
      ab, swq, sbq, swk, sbk, swv, sbv, sq16, sk16, sv);
  // 6. sv -> svT bf16 [b][625][512]
  transpose_bat<__bf16><<<dim3(10, 8, BATCH), 256, 0, stream>>>(sv, svT, CH, NPIX);
  // 7. weight casts + BN fold
  cast_bf16_kernel<<<1024, 256, 0, stream>>>(proj_w, pw16, CH * CH);
  cast_bf16_kernel<<<4096, 256, 0, stream>>>(w1, w116, HIDD * CH);
  cast_bf16_kernel<<<4096, 256, 0, stream>>>(w2, w216, CH * HIDD);
  bn_prep<<<2, 256, 0, stream>>>(bn_g, bn_b, bn_m, bn_v, bnsc, bnsh);
  // 8. channel attention v2 (4-wave cooperative) -> Amat bf16 [b][512][512]
  chan_attn_mfma2<<<dim3(32, BATCH), 256, 0, stream>>>(sq16, sk16, Amat);
  // 9. G1: xoutT[b] = svT (625x512) . Amat^T -> bf16 [b][625][512]
  gemm_nt<0><<<dim3(8, 5, BATCH), 256, 0, stream>>>(
      svT, (long long)NPIX * CH, Amat, (long long)CH * CH,
      xoutT, (long long)NPIX * CH, NPIX, CH, CH,
      nullptr, nullptr, nullptr, 0);
  // 10. x -> x_nc f32 [b][625][512]
  transpose_bat<float><<<dim3(10, 8, BATCH), 256, 0, stream>>>(x, x_nc, CH, NPIX);
  // 11. G2: y1_nc = BN(xoutT . pw16^T) + x_nc   (f32, [10000][512])
  gemm_nt<1><<<dim3(8, 79, 1), 256, 0, stream>>>(
      xoutT, 0LL, pw16, 0LL, y1_nc, 0LL, BATCH * NPIX, CH, CH,
      bnsc, bnsh, x_nc, 0LL);
  // 12. LN2 (row-wise) -> y1ln bf16
  ln2_row_kernel<<<BATCH * NPIX / 4, 256, 0, stream>>>(y1_nc, ln2_g, ln2_b, y1ln);
  // 13. G3: h1T = gelu(y1ln . w116^T + b1)  bf16 [10000][2048]
  gemm_nt<2><<<dim3(32, 79, 1), 256, 0, stream>>>(
      y1ln, 0LL, w116, 0LL, h1T, 0LL, BATCH * NPIX, HIDD, CH,
      b1, nullptr, nullptr, 0LL);
  // 14. G4: tmp_nc = h1T . w216^T + b2 + y1_nc  (f32 [10000][512])
  gemm_nt<3><<<dim3(8, 79, 1), 256, 0, stream>>>(
      h1T, 0LL, w216, 0LL, tmp_nc, 0LL, BATCH * NPIX, CH, HIDD,
      b2, nullptr, y1_nc, 0LL);
  // 15. tmp_nc [b][625][512] -> d_out [b][512][625]
  transpose_bat<float><<<dim3(8, 10, BATCH), 256, 0, stream>>>(
      tmp_nc, (float*)d_out, NPIX, CH);
}